// Round 7
// baseline (522.271 us; speedup 1.0000x reference)
//
#include <hip/hip_runtime.h>
#include <hip/hip_bf16.h>

typedef float f32x4 __attribute__((ext_vector_type(4)));
typedef short s16x8 __attribute__((ext_vector_type(8)));
typedef short s16x4 __attribute__((ext_vector_type(4)));
typedef unsigned short u16;

#define H_ 16
#define E_ 64
#define D_ 1024
#define L_ 2048
#define NQT 32   // 64-row q tiles per (b,h)

__device__ __forceinline__ u16 f2bf(float f) {
  union { float f; unsigned u; } v; v.f = f;
  unsigned u = v.u;
  u += 0x7fffu + ((u >> 16) & 1u);   // round-to-nearest-even
  return (u16)(u >> 16);
}

// pack 2 f32 -> 2 bf16 in one u32 (lo=a, hi=b), RNE
__device__ __forceinline__ unsigned pkbf(float a, float b) {
  unsigned r;
  asm volatile("v_cvt_pk_bf16_f32 %0, %1, %2" : "=v"(r) : "v"(a), "v"(b));
  return r;
}

// out = A (M x K) * W^T + bias,  W is (N x K) row-major.
// A_BF16: A is bf16 (u16) else f32 (converted on the fly).
// PERMUTE: 0 = f32 row-major (M x N); 1 = bf16 (B,H,L,E); 2 = bf16 (B,H,E,L) (V^T).
template<int A_BF16, int PERMUTE>
__global__ __launch_bounds__(256) void gemm_bt(const void* __restrict__ Aptr,
                                               const float* __restrict__ W,
                                               const float* __restrict__ bias,
                                               void* __restrict__ outp,
                                               int M, int N, int K)
{
  __shared__ __align__(16) short As[128][40];   // +8 pad: 80B stride -> 2-way (free)
  __shared__ __align__(16) short Bs[128][40];
  const int tid = threadIdx.x;
  const int m0 = blockIdx.y * 128, n0 = blockIdx.x * 128;
  const int w = tid >> 6, lane = tid & 63, g = lane >> 4, li = lane & 15;
  const int wr = w >> 1, wc = w & 1;

  f32x4 acc[4][4];
#pragma unroll
  for (int i = 0; i < 4; ++i)
#pragma unroll
    for (int j = 0; j < 4; ++j) acc[i][j] = (f32x4){0.f, 0.f, 0.f, 0.f};

  for (int k0 = 0; k0 < K; k0 += 32) {
    __syncthreads();
#pragma unroll
    for (int p = 0; p < 2; ++p) {
      const int c = p * 256 + tid;          // 512 chunks of 8 elems
      const int row = c >> 2, kc = (c & 3) * 8;
      if (A_BF16) {
        const u16* ap = (const u16*)Aptr + (size_t)(m0 + row) * K + k0 + kc;
        *(s16x8*)&As[row][kc] = *(const s16x8*)ap;
      } else {
        const float* ap = (const float*)Aptr + (size_t)(m0 + row) * K + k0 + kc;
        f32x4 f0 = *(const f32x4*)ap, f1 = *(const f32x4*)(ap + 4);
        union { s16x8 v; unsigned u[4]; } U;
        U.u[0] = pkbf(f0[0], f0[1]); U.u[1] = pkbf(f0[2], f0[3]);
        U.u[2] = pkbf(f1[0], f1[1]); U.u[3] = pkbf(f1[2], f1[3]);
        *(s16x8*)&As[row][kc] = U.v;
      }
      const float* wp = W + (size_t)(n0 + row) * K + k0 + kc;
      f32x4 g0 = *(const f32x4*)wp, g1 = *(const f32x4*)(wp + 4);
      union { s16x8 v; unsigned u[4]; } UB;
      UB.u[0] = pkbf(g0[0], g0[1]); UB.u[1] = pkbf(g0[2], g0[3]);
      UB.u[2] = pkbf(g1[0], g1[1]); UB.u[3] = pkbf(g1[2], g1[3]);
      *(s16x8*)&Bs[row][kc] = UB.v;
    }
    __syncthreads();

    s16x8 a[4], b[4];
#pragma unroll
    for (int mi = 0; mi < 4; ++mi) a[mi] = *(const s16x8*)&As[wr * 64 + mi * 16 + li][g * 8];
#pragma unroll
    for (int ni = 0; ni < 4; ++ni) b[ni] = *(const s16x8*)&Bs[wc * 64 + ni * 16 + li][g * 8];
#pragma unroll
    for (int mi = 0; mi < 4; ++mi)
#pragma unroll
      for (int ni = 0; ni < 4; ++ni)
        acc[mi][ni] = __builtin_amdgcn_mfma_f32_16x16x32_bf16(a[mi], b[ni], acc[mi][ni], 0, 0, 0);
  }

#pragma unroll
  for (int mi = 0; mi < 4; ++mi) {
#pragma unroll
    for (int ni = 0; ni < 4; ++ni) {
      const int row = m0 + wr * 64 + mi * 16 + g * 4;
      const int col = n0 + wc * 64 + ni * 16 + li;
      const float bv = bias[col];
      if (PERMUTE == 2) {
        union { s16x4 v; unsigned u[2]; } P;
        P.u[0] = pkbf(acc[mi][ni][0] + bv, acc[mi][ni][1] + bv);
        P.u[1] = pkbf(acc[mi][ni][2] + bv, acc[mi][ni][3] + bv);
        const int bb = row >> 11, lq = row & (L_ - 1);
        const int hh = col >> 6, e = col & (E_ - 1);
        *(s16x4*)&((u16*)outp)[(((size_t)bb * H_ + hh) * E_ + e) * L_ + lq] = P.v;
      } else {
#pragma unroll
        for (int r = 0; r < 4; ++r) {
          const float v = acc[mi][ni][r] + bv;
          const int rr = row + r;
          if (PERMUTE == 1) {
            const int bb = rr >> 11, lq = rr & (L_ - 1);
            const int hh = col >> 6, e = col & (E_ - 1);
            ((u16*)outp)[(((size_t)bb * H_ + hh) * L_ + lq) * E_ + e] = f2bf(v);
          } else {
            ((float*)outp)[(size_t)rr * N + col] = v;
          }
        }
      }
    }
  }
}

// Flash attention, causal. Grid: (NQT/2, B*H). Block: 256 (4 waves x 16 q rows).
// Swapped QK^T (S^T = K x Q^T): k-axis register-local. Two q-tiles {31-x, x}
// per block share K/V loads and run as two INDEPENDENT interleavable chains
// (separate Ps buffers). Defer-max (THR=8, log2 domain). alpha/l broadcast
// via shfl (no LDS round-trip). K reg-double-buffered.
__global__ __launch_bounds__(256) void attn_kernel(const u16* __restrict__ qp,
                                                   const u16* __restrict__ kp,
                                                   const u16* __restrict__ vtp,
                                                   u16* __restrict__ op)
{
  __shared__ __align__(16) short PsA[4][16][72];
  __shared__ __align__(16) short PsB[4][16][72];
  const int tid = threadIdx.x;
  const int bh = blockIdx.y;
  const int w = tid >> 6, lane = tid & 63, g = lane >> 4, li = lane & 15;
  const float scl2e = 0.125f * 1.44269504089f;    // (1/sqrt(E)) * log2(e)
  const size_t base  = (size_t)bh * L_ * E_;      // q,k: (B,H,L,E)
  const size_t baseT = (size_t)bh * E_ * L_;      // vt:  (B,H,E,L)
  const int bb = bh >> 4, hh = bh & 15;

  const int qbA = NQT - 1 - (int)blockIdx.x;      // 16..31 (long tile)
  const int qbB = (int)blockIdx.x;                // 0..15  (short tile)
  const int qbaseA = qbA * 64, qbaseB = qbB * 64;

  const u16* qrA = qp + base + (size_t)(qbaseA + w * 16 + li) * E_;
  const s16x8 qa0A = *(const s16x8*)(qrA + g * 8);
  const s16x8 qa1A = *(const s16x8*)(qrA + 32 + g * 8);
  const u16* qrB = qp + base + (size_t)(qbaseB + w * 16 + li) * E_;
  const s16x8 qa0B = *(const s16x8*)(qrB + g * 8);
  const s16x8 qa1B = *(const s16x8*)(qrB + 32 + g * 8);

  f32x4 oA[4], oB[4];
  float mA = -1e30f, lA = 0.f, mB = -1e30f, lB = 0.f;   // per-lane row stats (q=w*16+li)
#pragma unroll
  for (int nc = 0; nc < 4; ++nc) { oA[nc] = (f32x4){0.f,0.f,0.f,0.f}; oB[nc] = (f32x4){0.f,0.f,0.f,0.f}; }

  auto loadk = [&](s16x8* kf, int t) {
    const int kvb = t * 64;
#pragma unroll
    for (int kc = 0; kc < 4; ++kc) {
      const u16* krow = kp + base + (size_t)(kvb + kc * 16 + li) * E_;
      kf[kc * 2]     = *(const s16x8*)(krow + g * 8);
      kf[kc * 2 + 1] = *(const s16x8*)(krow + 32 + g * 8);
    }
  };

  // S^T = K*Q^T: lane (g,li) holds q-row (w*16+li), k = kc*16 + g*4 + r
  auto qk = [&](const s16x8* kf, const s16x8& q0, const s16x8& q1, float p[4][4]) {
#pragma unroll
    for (int kc = 0; kc < 4; ++kc) {
      f32x4 sf = (f32x4){0.f, 0.f, 0.f, 0.f};
      sf = __builtin_amdgcn_mfma_f32_16x16x32_bf16(kf[kc * 2],     q0, sf, 0, 0, 0);
      sf = __builtin_amdgcn_mfma_f32_16x16x32_bf16(kf[kc * 2 + 1], q1, sf, 0, 0, 0);
#pragma unroll
      for (int r = 0; r < 4; ++r) p[kc][r] = sf[r] * scl2e;
    }
  };

  // softmax in log2 domain + pack into Ps (writes issued per-kc, early).
  // Returns alpha (uniform-valid across g) and whether rescale happened.
  auto softmax = [&](float p[4][4], float& m_run, float& l_run,
                     short (*Psw)[72], float& alpha_out, bool& resc_out) {
    float m0_ = fmaxf(fmaxf(p[0][0], p[0][1]), fmaxf(p[0][2], p[0][3]));
    float m1_ = fmaxf(fmaxf(p[1][0], p[1][1]), fmaxf(p[1][2], p[1][3]));
    float m2_ = fmaxf(fmaxf(p[2][0], p[2][1]), fmaxf(p[2][2], p[2][3]));
    float m3_ = fmaxf(fmaxf(p[3][0], p[3][1]), fmaxf(p[3][2], p[3][3]));
    float mx = fmaxf(fmaxf(m0_, m1_), fmaxf(m2_, m3_));
    mx = fmaxf(mx, __shfl_xor(mx, 16));
    mx = fmaxf(mx, __shfl_xor(mx, 32));
    const bool resc = __any(mx > m_run + 8.0f);
    float alpha = 1.0f;
    if (resc) {
      const float mn = fmaxf(m_run, mx);
      alpha = __builtin_amdgcn_exp2f(m_run - mn);
      m_run = mn;
      l_run *= alpha;
    }
    float rs = 0.f;
#pragma unroll
    for (int kc = 0; kc < 4; ++kc) {
      float e0 = __builtin_amdgcn_exp2f(p[kc][0] - m_run);
      float e1 = __builtin_amdgcn_exp2f(p[kc][1] - m_run);
      float e2 = __builtin_amdgcn_exp2f(p[kc][2] - m_run);
      float e3 = __builtin_amdgcn_exp2f(p[kc][3] - m_run);
      rs += (e0 + e1) + (e2 + e3);
      union { s16x4 v; unsigned u[2]; } P;
      P.u[0] = pkbf(e0, e1); P.u[1] = pkbf(e2, e3);
      *(s16x4*)&Psw[li][kc * 16 + g * 4] = P.v;   // early LDS write
    }
    rs += __shfl_xor(rs, 16);
    rs += __shfl_xor(rs, 32);
    l_run += rs;
    alpha_out = alpha; resc_out = resc;
  };

  auto pv = [&](short (*Psw)[72], const s16x8* v0, const s16x8* v1,
                f32x4* o, float alpha, bool resc) {
    const s16x8 pa0 = *(const s16x8*)&Psw[li][g * 8];
    const s16x8 pa1 = *(const s16x8*)&Psw[li][32 + g * 8];
    if (resc) {
      f32x4 av;
#pragma unroll
      for (int r = 0; r < 4; ++r) av[r] = __shfl(alpha, g * 4 + r);
#pragma unroll
      for (int nc = 0; nc < 4; ++nc)
#pragma unroll
        for (int r = 0; r < 4; ++r) o[nc][r] *= av[r];
    }
#pragma unroll
    for (int nc = 0; nc < 4; ++nc) {
      o[nc] = __builtin_amdgcn_mfma_f32_16x16x32_bf16(pa0, v0[nc], o[nc], 0, 0, 0);
      o[nc] = __builtin_amdgcn_mfma_f32_16x16x32_bf16(pa1, v1[nc], o[nc], 0, 0, 0);
    }
  };

  auto process = [&](int t, const s16x8* kf) {
    const int kvb = t * 64;
    const bool doB = (t <= qbB);
    s16x8 v0[4], v1[4];
#pragma unroll
    for (int nc = 0; nc < 4; ++nc) {
      const u16* vrow = vtp + baseT + (size_t)(nc * 16 + li) * L_ + kvb;
      v0[nc] = *(const s16x8*)(vrow + g * 8);
      v1[nc] = *(const s16x8*)(vrow + 32 + g * 8);
    }
    float pA[4][4], pB[4][4];
    qk(kf, qa0A, qa1A, pA);
    if (doB) qk(kf, qa0B, qa1B, pB);
    if (t == qbA) {
      const int qrow = qbaseA + w * 16 + li;
#pragma unroll
      for (int kc = 0; kc < 4; ++kc)
#pragma unroll
        for (int r = 0; r < 4; ++r)
          if (kvb + kc * 16 + g * 4 + r > qrow) pA[kc][r] = -1e30f;
    }
    if (doB && t == qbB) {
      const int qrow = qbaseB + w * 16 + li;
#pragma unroll
      for (int kc = 0; kc < 4; ++kc)
#pragma unroll
        for (int r = 0; r < 4; ++r)
          if (kvb + kc * 16 + g * 4 + r > qrow) pB[kc][r] = -1e30f;
    }
    float aA, aB; bool rA, rB;
    softmax(pA, mA, lA, PsA[w], aA, rA);
    if (doB) softmax(pB, mB, lB, PsB[w], aB, rB);
    pv(PsA[w], v0, v1, oA, aA, rA);
    if (doB) pv(PsB[w], v0, v1, oB, aB, rB);
  };

  s16x8 kfA[8], kfB[8];
  loadk(kfA, 0);
  for (int t = 0; ; t += 2) {
    if (t + 1 <= qbA) loadk(kfB, t + 1);      // prefetch next tile's K
    process(t, kfA);
    if (t + 1 > qbA) break;
    if (t + 2 <= qbA) loadk(kfA, t + 2);      // prefetch t+2
    process(t + 1, kfB);
    if (t + 2 > qbA) break;
  }

  auto epilogue = [&](const f32x4* o, float l_run, int qbase) {
    f32x4 inv;
#pragma unroll
    for (int r = 0; r < 4; ++r) inv[r] = 1.0f / __shfl(l_run, g * 4 + r);
#pragma unroll
    for (int nc = 0; nc < 4; ++nc)
#pragma unroll
      for (int r = 0; r < 4; ++r) {
        const int rowq = qbase + w * 16 + g * 4 + r;
        op[((size_t)bb * L_ + rowq) * D_ + hh * E_ + nc * 16 + li] = f2bf(o[nc][r] * inv[r]);
      }
  };
  epilogue(oA, lA, qbaseA);
  epilogue(oB, lB, qbaseB);
}

extern "C" void kernel_launch(void* const* d_in, const int* in_sizes, int n_in,
                              void* d_out, int out_size, void* d_ws, size_t ws_size,
                              hipStream_t stream) {
  const float* queries = (const float*)d_in[0];
  const float* keys    = (const float*)d_in[1];
  const float* values  = (const float*)d_in[2];
  // d_in[3] = attn_mask: exact causal triu(k=1), applied analytically.
  const float* Wq = (const float*)d_in[4];
  const float* bq = (const float*)d_in[5];
  const float* Wk = (const float*)d_in[6];
  const float* bk = (const float*)d_in[7];
  const float* Wv = (const float*)d_in[8];
  const float* bv = (const float*)d_in[9];
  const float* Wo = (const float*)d_in[10];
  const float* bo = (const float*)d_in[11];

  const size_t MD = (size_t)8192 * 1024;
  u16* qbuf = (u16*)d_ws;          // (B,H,L,E) bf16
  u16* kbuf = qbuf + MD;           // (B,H,L,E) bf16
  u16* vbuf = kbuf + MD;           // (B,H,E,L) bf16 (V^T)
  u16* abuf = vbuf + MD;           // attn out (B*L, D) bf16

  dim3 blk(256);
  dim3 ggrid(8, 64);               // (N/128, M/128)
  gemm_bt<0, 1><<<ggrid, blk, 0, stream>>>(queries, Wq, bq, qbuf, 8192, 1024, 1024);
  gemm_bt<0, 1><<<ggrid, blk, 0, stream>>>(keys,    Wk, bk, kbuf, 8192, 1024, 1024);
  gemm_bt<0, 2><<<ggrid, blk, 0, stream>>>(values,  Wv, bv, vbuf, 8192, 1024, 1024);
  attn_kernel<<<dim3(NQT / 2, 64), blk, 0, stream>>>(qbuf, kbuf, vbuf, abuf);
  gemm_bt<1, 0><<<ggrid, blk, 0, stream>>>(abuf, Wo, bo, d_out, 8192, 1024, 1024);
}

// Round 8
// 410.855 us; speedup vs baseline: 1.2712x; 1.2712x over previous
//
#include <hip/hip_runtime.h>
#include <hip/hip_bf16.h>

typedef float f32x4 __attribute__((ext_vector_type(4)));
typedef short s16x8 __attribute__((ext_vector_type(8)));
typedef short s16x4 __attribute__((ext_vector_type(4)));
typedef unsigned short u16;

#define H_ 16
#define E_ 64
#define D_ 1024
#define L_ 2048
#define NQT 32   // 64-row q tiles per (b,h)

__device__ __forceinline__ u16 f2bf(float f) {
  union { float f; unsigned u; } v; v.f = f;
  unsigned u = v.u;
  u += 0x7fffu + ((u >> 16) & 1u);   // round-to-nearest-even
  return (u16)(u >> 16);
}

// pack 2 f32 -> 2 bf16 in one u32 (lo=a, hi=b). NON-volatile: schedulable.
__device__ __forceinline__ unsigned pkbf(float a, float b) {
  unsigned r;
  asm("v_cvt_pk_bf16_f32 %0, %1, %2" : "=v"(r) : "v"(a), "v"(b));
  return r;
}

// out = A (M x K) * W^T + bias,  W is (N x K) row-major.
// A_BF16: A is bf16 (u16) else f32 (converted on the fly, scalar f2bf —
// hand-written cvt_pk asm here regressed 67% (m240 anti-pattern)).
// PERMUTE: 0 = f32 row-major (M x N); 1 = bf16 (B,H,L,E); 2 = bf16 (B,H,E,L) (V^T).
template<int A_BF16, int PERMUTE>
__global__ __launch_bounds__(256) void gemm_bt(const void* __restrict__ Aptr,
                                               const float* __restrict__ W,
                                               const float* __restrict__ bias,
                                               void* __restrict__ outp,
                                               int M, int N, int K)
{
  __shared__ __align__(16) short As[128][40];   // +8 pad: 80B stride -> 2-way (free)
  __shared__ __align__(16) short Bs[128][40];
  const int tid = threadIdx.x;
  const int m0 = blockIdx.y * 128, n0 = blockIdx.x * 128;
  const int w = tid >> 6, lane = tid & 63, g = lane >> 4, li = lane & 15;
  const int wr = w >> 1, wc = w & 1;

  f32x4 acc[4][4];
#pragma unroll
  for (int i = 0; i < 4; ++i)
#pragma unroll
    for (int j = 0; j < 4; ++j) acc[i][j] = (f32x4){0.f, 0.f, 0.f, 0.f};

  for (int k0 = 0; k0 < K; k0 += 32) {
    __syncthreads();
#pragma unroll
    for (int p = 0; p < 2; ++p) {
      const int c = p * 256 + tid;          // 512 chunks of 8 elems
      const int row = c >> 2, kc = (c & 3) * 8;
      if (A_BF16) {
        const u16* ap = (const u16*)Aptr + (size_t)(m0 + row) * K + k0 + kc;
        *(s16x8*)&As[row][kc] = *(const s16x8*)ap;
      } else {
        const float* ap = (const float*)Aptr + (size_t)(m0 + row) * K + k0 + kc;
        f32x4 f0 = *(const f32x4*)ap, f1 = *(const f32x4*)(ap + 4);
        s16x8 r;
#pragma unroll
        for (int j = 0; j < 4; ++j) { r[j] = (short)f2bf(f0[j]); r[j + 4] = (short)f2bf(f1[j]); }
        *(s16x8*)&As[row][kc] = r;
      }
      const float* wp = W + (size_t)(n0 + row) * K + k0 + kc;
      f32x4 g0 = *(const f32x4*)wp, g1 = *(const f32x4*)(wp + 4);
      s16x8 rb;
#pragma unroll
      for (int j = 0; j < 4; ++j) { rb[j] = (short)f2bf(g0[j]); rb[j + 4] = (short)f2bf(g1[j]); }
      *(s16x8*)&Bs[row][kc] = rb;
    }
    __syncthreads();

    s16x8 a[4], b[4];
#pragma unroll
    for (int mi = 0; mi < 4; ++mi) a[mi] = *(const s16x8*)&As[wr * 64 + mi * 16 + li][g * 8];
#pragma unroll
    for (int ni = 0; ni < 4; ++ni) b[ni] = *(const s16x8*)&Bs[wc * 64 + ni * 16 + li][g * 8];
#pragma unroll
    for (int mi = 0; mi < 4; ++mi)
#pragma unroll
      for (int ni = 0; ni < 4; ++ni)
        acc[mi][ni] = __builtin_amdgcn_mfma_f32_16x16x32_bf16(a[mi], b[ni], acc[mi][ni], 0, 0, 0);
  }

#pragma unroll
  for (int mi = 0; mi < 4; ++mi) {
#pragma unroll
    for (int ni = 0; ni < 4; ++ni) {
      const int row = m0 + wr * 64 + mi * 16 + g * 4;
      const int col = n0 + wc * 64 + ni * 16 + li;
      const float bv = bias[col];
      if (PERMUTE == 2) {
        s16x4 pk;
#pragma unroll
        for (int r = 0; r < 4; ++r) pk[r] = (short)f2bf(acc[mi][ni][r] + bv);
        const int bb = row >> 11, lq = row & (L_ - 1);
        const int hh = col >> 6, e = col & (E_ - 1);
        *(s16x4*)&((u16*)outp)[(((size_t)bb * H_ + hh) * E_ + e) * L_ + lq] = pk;
      } else {
#pragma unroll
        for (int r = 0; r < 4; ++r) {
          const float v = acc[mi][ni][r] + bv;
          const int rr = row + r;
          if (PERMUTE == 1) {
            const int bb = rr >> 11, lq = rr & (L_ - 1);
            const int hh = col >> 6, e = col & (E_ - 1);
            ((u16*)outp)[(((size_t)bb * H_ + hh) * L_ + lq) * E_ + e] = f2bf(v);
          } else {
            ((float*)outp)[(size_t)rr * N + col] = v;
          }
        }
      }
    }
  }
}

// Flash attention, causal. Grid: (NQT/2, B*H). Block: 256 (4 waves x 16 q rows).
// ALL-REGISTER pipeline, zero LDS:
//  - Swapped QK^T (S^T = K x Q^T) with PERMUTED K-row feed:
//    A-row li of QK-MFMA inst gets K row kvb + 32*(inst>>1)+4*(inst&1)+8*(li>>2)+(li&3),
//    so S^T lands with k_local = 32*(inst>>1)+8g+4*(inst&1)+r — exactly PV's
//    B-fragment order (k=g*8+j). P goes exp2 -> cvt_pk -> PV operand, no LDS.
//  - PV computed as O^T = V^T x P^T (same fragments, swapped roles), so
//    softmax stats live at lane li = q: no cross-lane broadcast for alpha/l.
//  - Defer-max (THR=8, log2 domain). Two q-tiles {31-x, x} share K/V loads.
//  - K reg-double-buffered (prefetch t+1 during t).
__global__ __launch_bounds__(256) void attn_kernel(const u16* __restrict__ qp,
                                                   const u16* __restrict__ kp,
                                                   const u16* __restrict__ vtp,
                                                   u16* __restrict__ op)
{
  const int tid = threadIdx.x;
  const int bh = blockIdx.y;
  const int w = tid >> 6, lane = tid & 63, g = lane >> 4, li = lane & 15;
  const float scl2e = 0.125f * 1.44269504089f;    // (1/sqrt(E)) * log2(e)
  const size_t base  = (size_t)bh * L_ * E_;      // q,k: (B,H,L,E)
  const size_t baseT = (size_t)bh * E_ * L_;      // vt:  (B,H,E,L)
  const int bb = bh >> 4, hh = bh & 15;

  const int qbA = NQT - 1 - (int)blockIdx.x;      // 16..31 (long tile)
  const int qbB = (int)blockIdx.x;                // 0..15  (short tile)
  const int qbaseA = qbA * 64, qbaseB = qbB * 64;

  const u16* qrA = qp + base + (size_t)(qbaseA + w * 16 + li) * E_;
  const s16x8 qa0A = *(const s16x8*)(qrA + g * 8);
  const s16x8 qa1A = *(const s16x8*)(qrA + 32 + g * 8);
  const u16* qrB = qp + base + (size_t)(qbaseB + w * 16 + li) * E_;
  const s16x8 qa0B = *(const s16x8*)(qrB + g * 8);
  const s16x8 qa1B = *(const s16x8*)(qrB + 32 + g * 8);

  f32x4 oA[4], oB[4];
  float mA = -1e30f, lA = 0.f, mB = -1e30f, lB = 0.f;   // per-lane, q = w*16+li
#pragma unroll
  for (int nc = 0; nc < 4; ++nc) { oA[nc] = (f32x4){0.f,0.f,0.f,0.f}; oB[nc] = (f32x4){0.f,0.f,0.f,0.f}; }

  // permuted K load: A-row li of inst <- K row kvb + 32*(inst>>1)+4*(inst&1)+8*(li>>2)+(li&3)
  const int kro = 8 * (li >> 2) + (li & 3);
  auto loadk = [&](s16x8* kf, int t) {
    const int kvb = t * 64;
#pragma unroll
    for (int inst = 0; inst < 4; ++inst) {
      const u16* kr = kp + base + (size_t)(kvb + 32 * (inst >> 1) + 4 * (inst & 1) + kro) * E_;
      kf[inst * 2]     = *(const s16x8*)(kr + g * 8);
      kf[inst * 2 + 1] = *(const s16x8*)(kr + 32 + g * 8);
    }
  };

  // full attend of one q-tile vs KV tile t; P stays in registers
  auto attend = [&](int t, const s16x8* kf, const s16x8* v0, const s16x8* v1,
                    const s16x8& q0, const s16x8& q1,
                    f32x4* o, float& m_run, float& l_run, int qb, int qbase) {
    float p[4][4];   // [inst][r]: S^T for q=w*16+li, k_local = 32*(inst>>1)+8g+4*(inst&1)+r
#pragma unroll
    for (int inst = 0; inst < 4; ++inst) {
      f32x4 sf = (f32x4){0.f, 0.f, 0.f, 0.f};
      sf = __builtin_amdgcn_mfma_f32_16x16x32_bf16(kf[inst * 2],     q0, sf, 0, 0, 0);
      sf = __builtin_amdgcn_mfma_f32_16x16x32_bf16(kf[inst * 2 + 1], q1, sf, 0, 0, 0);
#pragma unroll
      for (int r = 0; r < 4; ++r) p[inst][r] = sf[r] * scl2e;
    }
    if (t == qb) {   // diagonal tile: causal mask (k > q -> -inf)
      const int qrow = qbase + w * 16 + li;
      const int kvb = t * 64;
#pragma unroll
      for (int inst = 0; inst < 4; ++inst)
#pragma unroll
        for (int r = 0; r < 4; ++r)
          if (kvb + 32 * (inst >> 1) + 8 * g + 4 * (inst & 1) + r > qrow) p[inst][r] = -1e30f;
    }
    // row max: in-register tree + 2 cross-g shfls (row q=li spans g only)
    float m0_ = fmaxf(fmaxf(p[0][0], p[0][1]), fmaxf(p[0][2], p[0][3]));
    float m1_ = fmaxf(fmaxf(p[1][0], p[1][1]), fmaxf(p[1][2], p[1][3]));
    float m2_ = fmaxf(fmaxf(p[2][0], p[2][1]), fmaxf(p[2][2], p[2][3]));
    float m3_ = fmaxf(fmaxf(p[3][0], p[3][1]), fmaxf(p[3][2], p[3][3]));
    float mx = fmaxf(fmaxf(m0_, m1_), fmaxf(m2_, m3_));
    mx = fmaxf(mx, __shfl_xor(mx, 16));
    mx = fmaxf(mx, __shfl_xor(mx, 32));
    const bool resc = __any(mx > m_run + 8.0f);   // defer-max, log2 domain
    if (resc) {
      const float mn = fmaxf(m_run, mx);
      const float alpha = __builtin_amdgcn_exp2f(m_run - mn);
      m_run = mn;
      l_run *= alpha;
#pragma unroll
      for (int nc = 0; nc < 4; ++nc)
#pragma unroll
        for (int r = 0; r < 4; ++r) o[nc][r] *= alpha;   // alpha per-lane (q=li)
    }
    float rs = 0.f;
    unsigned pk[8];
#pragma unroll
    for (int inst = 0; inst < 4; ++inst) {
      const float e0 = __builtin_amdgcn_exp2f(p[inst][0] - m_run);
      const float e1 = __builtin_amdgcn_exp2f(p[inst][1] - m_run);
      const float e2 = __builtin_amdgcn_exp2f(p[inst][2] - m_run);
      const float e3 = __builtin_amdgcn_exp2f(p[inst][3] - m_run);
      rs += (e0 + e1) + (e2 + e3);
      pk[inst * 2]     = pkbf(e0, e1);
      pk[inst * 2 + 1] = pkbf(e2, e3);
    }
    union { s16x8 v; unsigned u[4]; } A0, A1;
    A0.u[0] = pk[0]; A0.u[1] = pk[1]; A0.u[2] = pk[2]; A0.u[3] = pk[3];
    A1.u[0] = pk[4]; A1.u[1] = pk[5]; A1.u[2] = pk[6]; A1.u[3] = pk[7];
    // O^T += V^T * P^T  (v = A-operand, packed P = B-operand)
#pragma unroll
    for (int nc = 0; nc < 4; ++nc) {
      o[nc] = __builtin_amdgcn_mfma_f32_16x16x32_bf16(v0[nc], A0.v, o[nc], 0, 0, 0);
      o[nc] = __builtin_amdgcn_mfma_f32_16x16x32_bf16(v1[nc], A1.v, o[nc], 0, 0, 0);
    }
    rs += __shfl_xor(rs, 16);   // l update off the PV critical path
    rs += __shfl_xor(rs, 32);
    l_run += rs;
  };

  auto process = [&](int t, const s16x8* kf) {
    const int kvb = t * 64;
    const bool doB = (t <= qbB);
    s16x8 v0[4], v1[4];
#pragma unroll
    for (int nc = 0; nc < 4; ++nc) {
      const u16* vrow = vtp + baseT + (size_t)(nc * 16 + li) * L_ + kvb;
      v0[nc] = *(const s16x8*)(vrow + g * 8);
      v1[nc] = *(const s16x8*)(vrow + 32 + g * 8);
    }
    attend(t, kf, v0, v1, qa0A, qa1A, oA, mA, lA, qbA, qbaseA);
    if (doB) attend(t, kf, v0, v1, qa0B, qa1B, oB, mB, lB, qbB, qbaseB);
  };

  s16x8 kfA[8], kfB[8];
  loadk(kfA, 0);
  for (int t = 0; ; t += 2) {
    if (t + 1 <= qbA) loadk(kfB, t + 1);      // prefetch next tile's K
    process(t, kfA);
    if (t + 1 > qbA) break;
    if (t + 2 <= qbA) loadk(kfA, t + 2);      // prefetch t+2
    process(t + 1, kfB);
    if (t + 2 > qbA) break;
  }

  // O^T epilogue: lane holds O[q=w*16+li][e=nc*16+g*4+r]; stats per-lane.
  auto epilogue = [&](const f32x4* o, float l_run, int qbase) {
    const float inv = 1.0f / l_run;
    u16* orow = op + ((size_t)bb * L_ + qbase + w * 16 + li) * D_ + hh * E_;
#pragma unroll
    for (int nc = 0; nc < 4; ++nc) {
      union { s16x4 v; unsigned u[2]; } P;
      P.u[0] = pkbf(o[nc][0] * inv, o[nc][1] * inv);
      P.u[1] = pkbf(o[nc][2] * inv, o[nc][3] * inv);
      *(s16x4*)&orow[nc * 16 + g * 4] = P.v;
    }
  };
  epilogue(oA, lA, qbaseA);
  epilogue(oB, lB, qbaseB);
}

extern "C" void kernel_launch(void* const* d_in, const int* in_sizes, int n_in,
                              void* d_out, int out_size, void* d_ws, size_t ws_size,
                              hipStream_t stream) {
  const float* queries = (const float*)d_in[0];
  const float* keys    = (const float*)d_in[1];
  const float* values  = (const float*)d_in[2];
  // d_in[3] = attn_mask: exact causal triu(k=1), applied analytically.
  const float* Wq = (const float*)d_in[4];
  const float* bq = (const float*)d_in[5];
  const float* Wk = (const float*)d_in[6];
  const float* bk = (const float*)d_in[7];
  const float* Wv = (const float*)d_in[8];
  const float* bv = (const float*)d_in[9];
  const float* Wo = (const float*)d_in[10];
  const float* bo = (const float*)d_in[11];

  const size_t MD = (size_t)8192 * 1024;
  u16* qbuf = (u16*)d_ws;          // (B,H,L,E) bf16
  u16* kbuf = qbuf + MD;           // (B,H,L,E) bf16
  u16* vbuf = kbuf + MD;           // (B,H,E,L) bf16 (V^T)
  u16* abuf = vbuf + MD;           // attn out (B*L, D) bf16

  dim3 blk(256);
  dim3 ggrid(8, 64);               // (N/128, M/128)
  gemm_bt<0, 1><<<ggrid, blk, 0, stream>>>(queries, Wq, bq, qbuf, 8192, 1024, 1024);
  gemm_bt<0, 1><<<ggrid, blk, 0, stream>>>(keys,    Wk, bk, kbuf, 8192, 1024, 1024);
  gemm_bt<0, 2><<<ggrid, blk, 0, stream>>>(values,  Wv, bv, vbuf, 8192, 1024, 1024);
  attn_kernel<<<dim3(NQT / 2, 64), blk, 0, stream>>>(qbuf, kbuf, vbuf, abuf);
  gemm_bt<1, 0><<<ggrid, blk, 0, stream>>>(abuf, Wo, bo, d_out, 8192, 1024, 1024);
}

// Round 9
// 363.443 us; speedup vs baseline: 1.4370x; 1.1305x over previous
//
#include <hip/hip_runtime.h>
#include <hip/hip_bf16.h>

typedef float f32x4 __attribute__((ext_vector_type(4)));
typedef short s16x8 __attribute__((ext_vector_type(8)));
typedef short s16x4 __attribute__((ext_vector_type(4)));
typedef unsigned short u16;

#define H_ 16
#define E_ 64
#define D_ 1024
#define L_ 2048
#define NQT 32   // 64-row q tiles per (b,h)

__device__ __forceinline__ u16 f2bf(float f) {
  union { float f; unsigned u; } v; v.f = f;
  unsigned u = v.u;
  u += 0x7fffu + ((u >> 16) & 1u);   // round-to-nearest-even
  return (u16)(u >> 16);
}

// pack 2 f32 -> 2 bf16 in one u32 (lo=a, hi=b). NON-volatile: schedulable.
__device__ __forceinline__ unsigned pkbf(float a, float b) {
  unsigned r;
  asm("v_cvt_pk_bf16_f32 %0, %1, %2" : "=v"(r) : "v"(a), "v"(b));
  return r;
}

// out = A (M x K) * W^T + bias,  W is (N x K) row-major.
// A_BF16: A is bf16 (u16) else f32 (converted on the fly, scalar f2bf —
// hand-written cvt_pk asm here regressed 67% (m240 anti-pattern)).
// PERMUTE: 0 = f32 row-major (M x N); 1 = bf16 (B,H,L,E); 2 = bf16 (B,H,E,L) (V^T).
template<int A_BF16, int PERMUTE>
__global__ __launch_bounds__(256) void gemm_bt(const void* __restrict__ Aptr,
                                               const float* __restrict__ W,
                                               const float* __restrict__ bias,
                                               void* __restrict__ outp,
                                               int M, int N, int K)
{
  __shared__ __align__(16) short As[128][40];   // +8 pad: 80B stride -> 2-way (free)
  __shared__ __align__(16) short Bs[128][40];
  const int tid = threadIdx.x;
  const int m0 = blockIdx.y * 128, n0 = blockIdx.x * 128;
  const int w = tid >> 6, lane = tid & 63, g = lane >> 4, li = lane & 15;
  const int wr = w >> 1, wc = w & 1;

  f32x4 acc[4][4];
#pragma unroll
  for (int i = 0; i < 4; ++i)
#pragma unroll
    for (int j = 0; j < 4; ++j) acc[i][j] = (f32x4){0.f, 0.f, 0.f, 0.f};

  for (int k0 = 0; k0 < K; k0 += 32) {
    __syncthreads();
#pragma unroll
    for (int p = 0; p < 2; ++p) {
      const int c = p * 256 + tid;          // 512 chunks of 8 elems
      const int row = c >> 2, kc = (c & 3) * 8;
      if (A_BF16) {
        const u16* ap = (const u16*)Aptr + (size_t)(m0 + row) * K + k0 + kc;
        *(s16x8*)&As[row][kc] = *(const s16x8*)ap;
      } else {
        const float* ap = (const float*)Aptr + (size_t)(m0 + row) * K + k0 + kc;
        f32x4 f0 = *(const f32x4*)ap, f1 = *(const f32x4*)(ap + 4);
        s16x8 r;
#pragma unroll
        for (int j = 0; j < 4; ++j) { r[j] = (short)f2bf(f0[j]); r[j + 4] = (short)f2bf(f1[j]); }
        *(s16x8*)&As[row][kc] = r;
      }
      const float* wp = W + (size_t)(n0 + row) * K + k0 + kc;
      f32x4 g0 = *(const f32x4*)wp, g1 = *(const f32x4*)(wp + 4);
      s16x8 rb;
#pragma unroll
      for (int j = 0; j < 4; ++j) { rb[j] = (short)f2bf(g0[j]); rb[j + 4] = (short)f2bf(g1[j]); }
      *(s16x8*)&Bs[row][kc] = rb;
    }
    __syncthreads();

    s16x8 a[4], b[4];
#pragma unroll
    for (int mi = 0; mi < 4; ++mi) a[mi] = *(const s16x8*)&As[wr * 64 + mi * 16 + li][g * 8];
#pragma unroll
    for (int ni = 0; ni < 4; ++ni) b[ni] = *(const s16x8*)&Bs[wc * 64 + ni * 16 + li][g * 8];
#pragma unroll
    for (int mi = 0; mi < 4; ++mi)
#pragma unroll
      for (int ni = 0; ni < 4; ++ni)
        acc[mi][ni] = __builtin_amdgcn_mfma_f32_16x16x32_bf16(a[mi], b[ni], acc[mi][ni], 0, 0, 0);
  }

#pragma unroll
  for (int mi = 0; mi < 4; ++mi) {
#pragma unroll
    for (int ni = 0; ni < 4; ++ni) {
      const int row = m0 + wr * 64 + mi * 16 + g * 4;
      const int col = n0 + wc * 64 + ni * 16 + li;
      const float bv = bias[col];
      if (PERMUTE == 2) {
        s16x4 pk;
#pragma unroll
        for (int r = 0; r < 4; ++r) pk[r] = (short)f2bf(acc[mi][ni][r] + bv);
        const int bb = row >> 11, lq = row & (L_ - 1);
        const int hh = col >> 6, e = col & (E_ - 1);
        *(s16x4*)&((u16*)outp)[(((size_t)bb * H_ + hh) * E_ + e) * L_ + lq] = pk;
      } else {
#pragma unroll
        for (int r = 0; r < 4; ++r) {
          const float v = acc[mi][ni][r] + bv;
          const int rr = row + r;
          if (PERMUTE == 1) {
            const int bb = rr >> 11, lq = rr & (L_ - 1);
            const int hh = col >> 6, e = col & (E_ - 1);
            ((u16*)outp)[(((size_t)bb * H_ + hh) * L_ + lq) * E_ + e] = f2bf(v);
          } else {
            ((float*)outp)[(size_t)rr * N + col] = v;
          }
        }
      }
    }
  }
}

// Flash attention, causal. Grid: 1024 blocks (1D). Block: 256 (4 waves x 16 q rows).
// XCD-grouped: hardware assigns xcd = wgid%8 (round-robin); remap so XCD c owns
// bh in [8c,8c+8) -> per-XCD K/V working set = 8*512KB = 4MB = one L2.
// ALL-REGISTER pipeline, zero LDS (see R8 notes). K AND V reg-double-buffered:
// V(t+1) prefetched with K(t+1), so PV operands are a full iteration old.
__global__ __launch_bounds__(256) void attn_kernel(const u16* __restrict__ qp,
                                                   const u16* __restrict__ kp,
                                                   const u16* __restrict__ vtp,
                                                   u16* __restrict__ op)
{
  const int tid = threadIdx.x;
  const unsigned wgid = blockIdx.x;
  const int bh = (wgid & 7) * 8 + ((wgid >> 3) & 7);   // XCD c -> bh in [8c, 8c+8)
  const int qx = wgid >> 6;                            // 0..15
  const int w = tid >> 6, lane = tid & 63, g = lane >> 4, li = lane & 15;
  const float scl2e = 0.125f * 1.44269504089f;    // (1/sqrt(E)) * log2(e)
  const size_t base  = (size_t)bh * L_ * E_;      // q,k: (B,H,L,E)
  const size_t baseT = (size_t)bh * E_ * L_;      // vt:  (B,H,E,L)
  const int bb = bh >> 4, hh = bh & 15;

  const int qbA = NQT - 1 - qx;                   // 16..31 (long tile)
  const int qbB = qx;                             // 0..15  (short tile)
  const int qbaseA = qbA * 64, qbaseB = qbB * 64;

  const u16* qrA = qp + base + (size_t)(qbaseA + w * 16 + li) * E_;
  const s16x8 qa0A = *(const s16x8*)(qrA + g * 8);
  const s16x8 qa1A = *(const s16x8*)(qrA + 32 + g * 8);
  const u16* qrB = qp + base + (size_t)(qbaseB + w * 16 + li) * E_;
  const s16x8 qa0B = *(const s16x8*)(qrB + g * 8);
  const s16x8 qa1B = *(const s16x8*)(qrB + 32 + g * 8);

  f32x4 oA[4], oB[4];
  float mA = -1e30f, lA = 0.f, mB = -1e30f, lB = 0.f;   // per-lane, q = w*16+li
#pragma unroll
  for (int nc = 0; nc < 4; ++nc) { oA[nc] = (f32x4){0.f,0.f,0.f,0.f}; oB[nc] = (f32x4){0.f,0.f,0.f,0.f}; }

  // permuted K load: A-row li of inst <- K row kvb + 32*(inst>>1)+4*(inst&1)+8*(li>>2)+(li&3)
  const int kro = 8 * (li >> 2) + (li & 3);
  auto loadk = [&](s16x8* kf, int t) {
    const int kvb = t * 64;
#pragma unroll
    for (int inst = 0; inst < 4; ++inst) {
      const u16* kr = kp + base + (size_t)(kvb + 32 * (inst >> 1) + 4 * (inst & 1) + kro) * E_;
      kf[inst * 2]     = *(const s16x8*)(kr + g * 8);
      kf[inst * 2 + 1] = *(const s16x8*)(kr + 32 + g * 8);
    }
  };
  auto loadv = [&](s16x8* vf, int t) {
    const int kvb = t * 64;
#pragma unroll
    for (int nc = 0; nc < 4; ++nc) {
      const u16* vrow = vtp + baseT + (size_t)(nc * 16 + li) * L_ + kvb;
      vf[nc * 2]     = *(const s16x8*)(vrow + g * 8);
      vf[nc * 2 + 1] = *(const s16x8*)(vrow + 32 + g * 8);
    }
  };

  // full attend of one q-tile vs KV tile t; P stays in registers
  auto attend = [&](int t, const s16x8* kf, const s16x8* vf,
                    const s16x8& q0, const s16x8& q1,
                    f32x4* o, float& m_run, float& l_run, int qb, int qbase) {
    float p[4][4];   // [inst][r]: S^T for q=w*16+li, k_local = 32*(inst>>1)+8g+4*(inst&1)+r
#pragma unroll
    for (int inst = 0; inst < 4; ++inst) {
      f32x4 sf = (f32x4){0.f, 0.f, 0.f, 0.f};
      sf = __builtin_amdgcn_mfma_f32_16x16x32_bf16(kf[inst * 2],     q0, sf, 0, 0, 0);
      sf = __builtin_amdgcn_mfma_f32_16x16x32_bf16(kf[inst * 2 + 1], q1, sf, 0, 0, 0);
#pragma unroll
      for (int r = 0; r < 4; ++r) p[inst][r] = sf[r] * scl2e;
    }
    if (t == qb) {   // diagonal tile: causal mask (k > q -> -inf)
      const int qrow = qbase + w * 16 + li;
      const int kvb = t * 64;
#pragma unroll
      for (int inst = 0; inst < 4; ++inst)
#pragma unroll
        for (int r = 0; r < 4; ++r)
          if (kvb + 32 * (inst >> 1) + 8 * g + 4 * (inst & 1) + r > qrow) p[inst][r] = -1e30f;
    }
    // row max: in-register tree + 2 cross-g shfls (row q=li spans g only)
    float m0_ = fmaxf(fmaxf(p[0][0], p[0][1]), fmaxf(p[0][2], p[0][3]));
    float m1_ = fmaxf(fmaxf(p[1][0], p[1][1]), fmaxf(p[1][2], p[1][3]));
    float m2_ = fmaxf(fmaxf(p[2][0], p[2][1]), fmaxf(p[2][2], p[2][3]));
    float m3_ = fmaxf(fmaxf(p[3][0], p[3][1]), fmaxf(p[3][2], p[3][3]));
    float mx = fmaxf(fmaxf(m0_, m1_), fmaxf(m2_, m3_));
    mx = fmaxf(mx, __shfl_xor(mx, 16));
    mx = fmaxf(mx, __shfl_xor(mx, 32));
    const bool resc = __any(mx > m_run + 8.0f);   // defer-max, log2 domain
    if (resc) {
      const float mn = fmaxf(m_run, mx);
      const float alpha = __builtin_amdgcn_exp2f(m_run - mn);
      m_run = mn;
      l_run *= alpha;
#pragma unroll
      for (int nc = 0; nc < 4; ++nc)
#pragma unroll
        for (int r = 0; r < 4; ++r) o[nc][r] *= alpha;   // alpha per-lane (q=li)
    }
    float rs = 0.f;
    unsigned pk[8];
#pragma unroll
    for (int inst = 0; inst < 4; ++inst) {
      const float e0 = __builtin_amdgcn_exp2f(p[inst][0] - m_run);
      const float e1 = __builtin_amdgcn_exp2f(p[inst][1] - m_run);
      const float e2 = __builtin_amdgcn_exp2f(p[inst][2] - m_run);
      const float e3 = __builtin_amdgcn_exp2f(p[inst][3] - m_run);
      rs += (e0 + e1) + (e2 + e3);
      pk[inst * 2]     = pkbf(e0, e1);
      pk[inst * 2 + 1] = pkbf(e2, e3);
    }
    union { s16x8 v; unsigned u[4]; } A0, A1;
    A0.u[0] = pk[0]; A0.u[1] = pk[1]; A0.u[2] = pk[2]; A0.u[3] = pk[3];
    A1.u[0] = pk[4]; A1.u[1] = pk[5]; A1.u[2] = pk[6]; A1.u[3] = pk[7];
    // O^T += V^T * P^T  (v = A-operand, packed P = B-operand)
#pragma unroll
    for (int nc = 0; nc < 4; ++nc) {
      o[nc] = __builtin_amdgcn_mfma_f32_16x16x32_bf16(vf[nc * 2],     A0.v, o[nc], 0, 0, 0);
      o[nc] = __builtin_amdgcn_mfma_f32_16x16x32_bf16(vf[nc * 2 + 1], A1.v, o[nc], 0, 0, 0);
    }
    rs += __shfl_xor(rs, 16);   // l update off the PV critical path
    rs += __shfl_xor(rs, 32);
    l_run += rs;
  };

  auto process = [&](int t, const s16x8* kf, const s16x8* vf) {
    attend(t, kf, vf, qa0A, qa1A, oA, mA, lA, qbA, qbaseA);
    if (t <= qbB) attend(t, kf, vf, qa0B, qa1B, oB, mB, lB, qbB, qbaseB);
  };

  s16x8 kfA[8], kfB[8], vfA[8], vfB[8];
  loadk(kfA, 0); loadv(vfA, 0);
  for (int t = 0; ; t += 2) {
    if (t + 1 <= qbA) { loadk(kfB, t + 1); loadv(vfB, t + 1); }   // prefetch t+1
    process(t, kfA, vfA);
    if (t + 1 > qbA) break;
    if (t + 2 <= qbA) { loadk(kfA, t + 2); loadv(vfA, t + 2); }   // prefetch t+2
    process(t + 1, kfB, vfB);
    if (t + 2 > qbA) break;
  }

  // O^T epilogue: lane holds O[q=w*16+li][e=nc*16+g*4+r]; stats per-lane.
  auto epilogue = [&](const f32x4* o, float l_run, int qbase) {
    const float inv = 1.0f / l_run;
    u16* orow = op + ((size_t)bb * L_ + qbase + w * 16 + li) * D_ + hh * E_;
#pragma unroll
    for (int nc = 0; nc < 4; ++nc) {
      union { s16x4 v; unsigned u[2]; } P;
      P.u[0] = pkbf(o[nc][0] * inv, o[nc][1] * inv);
      P.u[1] = pkbf(o[nc][2] * inv, o[nc][3] * inv);
      *(s16x4*)&orow[nc * 16 + g * 4] = P.v;
    }
  };
  epilogue(oA, lA, qbaseA);
  epilogue(oB, lB, qbaseB);
}

extern "C" void kernel_launch(void* const* d_in, const int* in_sizes, int n_in,
                              void* d_out, int out_size, void* d_ws, size_t ws_size,
                              hipStream_t stream) {
  const float* queries = (const float*)d_in[0];
  const float* keys    = (const float*)d_in[1];
  const float* values  = (const float*)d_in[2];
  // d_in[3] = attn_mask: exact causal triu(k=1), applied analytically.
  const float* Wq = (const float*)d_in[4];
  const float* bq = (const float*)d_in[5];
  const float* Wk = (const float*)d_in[6];
  const float* bk = (const float*)d_in[7];
  const float* Wv = (const float*)d_in[8];
  const float* bv = (const float*)d_in[9];
  const float* Wo = (const float*)d_in[10];
  const float* bo = (const float*)d_in[11];

  const size_t MD = (size_t)8192 * 1024;
  u16* qbuf = (u16*)d_ws;          // (B,H,L,E) bf16
  u16* kbuf = qbuf + MD;           // (B,H,L,E) bf16
  u16* vbuf = kbuf + MD;           // (B,H,E,L) bf16 (V^T)
  u16* abuf = vbuf + MD;           // attn out (B*L, D) bf16

  dim3 blk(256);
  dim3 ggrid(8, 64);               // (N/128, M/128)
  gemm_bt<0, 1><<<ggrid, blk, 0, stream>>>(queries, Wq, bq, qbuf, 8192, 1024, 1024);
  gemm_bt<0, 1><<<ggrid, blk, 0, stream>>>(keys,    Wk, bk, kbuf, 8192, 1024, 1024);
  gemm_bt<0, 2><<<ggrid, blk, 0, stream>>>(values,  Wv, bv, vbuf, 8192, 1024, 1024);
  attn_kernel<<<dim3(1024), blk, 0, stream>>>(qbuf, kbuf, vbuf, abuf);
  gemm_bt<1, 0><<<ggrid, blk, 0, stream>>>(abuf, Wo, bo, d_out, 8192, 1024, 1024);
}

// Round 10
// 349.226 us; speedup vs baseline: 1.4955x; 1.0407x over previous
//
#include <hip/hip_runtime.h>
#include <hip/hip_bf16.h>

typedef float f32x4 __attribute__((ext_vector_type(4)));
typedef short s16x8 __attribute__((ext_vector_type(8)));
typedef short s16x4 __attribute__((ext_vector_type(4)));
typedef unsigned short u16;

#define H_ 16
#define E_ 64
#define D_ 1024
#define L_ 2048
#define NQT 32   // 64-row q tiles per (b,h)

__device__ __forceinline__ u16 f2bf(float f) {
  union { float f; unsigned u; } v; v.f = f;
  unsigned u = v.u;
  u += 0x7fffu + ((u >> 16) & 1u);   // round-to-nearest-even
  return (u16)(u >> 16);
}

// pack 2 f32 -> 2 bf16 in one u32 (lo=a, hi=b). NON-volatile: schedulable.
__device__ __forceinline__ unsigned pkbf(float a, float b) {
  unsigned r;
  asm("v_cvt_pk_bf16_f32 %0, %1, %2" : "=v"(r) : "v"(a), "v"(b));
  return r;
}

// out = A (M x K) * W^T + bias,  W is (N x K) row-major.
// T14-split staging: issue tile k+1 global loads BEFORE compute(k), convert +
// LDS-write after compute, LDS double-buffered, ONE barrier per K-step.
// A_BF16: A is bf16 (u16) else f32. PERMUTE: 0 = f32 (M x N); 1 = bf16
// (B,H,L,E); 2 = bf16 (B,H,E,L) (V^T).
template<int A_BF16, int PERMUTE>
__global__ __launch_bounds__(256) void gemm_bt(const void* __restrict__ Aptr,
                                               const float* __restrict__ W,
                                               const float* __restrict__ bias,
                                               void* __restrict__ outp,
                                               int M, int N, int K)
{
  __shared__ __align__(16) short As[2][128][40];   // +8 pad: 80B stride, 2-way (free)
  __shared__ __align__(16) short Bs[2][128][40];
  const int tid = threadIdx.x;
  const int m0 = blockIdx.y * 128, n0 = blockIdx.x * 128;
  const int w = tid >> 6, lane = tid & 63, g = lane >> 4, li = lane & 15;
  const int wr = w >> 1, wc = w & 1;

  f32x4 acc[4][4];
#pragma unroll
  for (int i = 0; i < 4; ++i)
#pragma unroll
    for (int j = 0; j < 4; ++j) acc[i][j] = (f32x4){0.f, 0.f, 0.f, 0.f};

  // staging registers for one K-tile (2 chunks of 8 elems each for A and W)
  f32x4 ra0[2], ra1[2];   // f32 A path
  s16x8 rab[2];           // bf16 A path
  f32x4 rb0[2], rb1[2];   // W (always f32)

  auto LOAD = [&](int k0) {
#pragma unroll
    for (int p = 0; p < 2; ++p) {
      const int c = p * 256 + tid, row = c >> 2, kc = (c & 3) * 8;
      if (A_BF16) {
        rab[p] = *(const s16x8*)((const u16*)Aptr + (size_t)(m0 + row) * K + k0 + kc);
      } else {
        const float* ap = (const float*)Aptr + (size_t)(m0 + row) * K + k0 + kc;
        ra0[p] = *(const f32x4*)ap; ra1[p] = *(const f32x4*)(ap + 4);
      }
      const float* wp = W + (size_t)(n0 + row) * K + k0 + kc;
      rb0[p] = *(const f32x4*)wp; rb1[p] = *(const f32x4*)(wp + 4);
    }
  };
  auto WRITE = [&](int buf) {
#pragma unroll
    for (int p = 0; p < 2; ++p) {
      const int c = p * 256 + tid, row = c >> 2, kc = (c & 3) * 8;
      if (A_BF16) {
        *(s16x8*)&As[buf][row][kc] = rab[p];
      } else {
        s16x8 r;
#pragma unroll
        for (int j = 0; j < 4; ++j) { r[j] = (short)f2bf(ra0[p][j]); r[j + 4] = (short)f2bf(ra1[p][j]); }
        *(s16x8*)&As[buf][row][kc] = r;
      }
      s16x8 rb;
#pragma unroll
      for (int j = 0; j < 4; ++j) { rb[j] = (short)f2bf(rb0[p][j]); rb[j + 4] = (short)f2bf(rb1[p][j]); }
      *(s16x8*)&Bs[buf][row][kc] = rb;
    }
  };

  LOAD(0); WRITE(0);
  __syncthreads();
  int cur = 0;
  for (int k0 = 0; k0 < K; k0 += 32) {
    const bool more = (k0 + 32 < K);
    if (more) LOAD(k0 + 32);              // in flight during compute

    s16x8 a[4], b[4];
#pragma unroll
    for (int mi = 0; mi < 4; ++mi) a[mi] = *(const s16x8*)&As[cur][wr * 64 + mi * 16 + li][g * 8];
#pragma unroll
    for (int ni = 0; ni < 4; ++ni) b[ni] = *(const s16x8*)&Bs[cur][wc * 64 + ni * 16 + li][g * 8];
#pragma unroll
    for (int mi = 0; mi < 4; ++mi)
#pragma unroll
      for (int ni = 0; ni < 4; ++ni)
        acc[mi][ni] = __builtin_amdgcn_mfma_f32_16x16x32_bf16(a[mi], b[ni], acc[mi][ni], 0, 0, 0);

    if (more) {
      WRITE(cur ^ 1);                     // vmcnt drained here, after compute
      __syncthreads();
    }
    cur ^= 1;
  }

#pragma unroll
  for (int mi = 0; mi < 4; ++mi) {
#pragma unroll
    for (int ni = 0; ni < 4; ++ni) {
      const int row = m0 + wr * 64 + mi * 16 + g * 4;
      const int col = n0 + wc * 64 + ni * 16 + li;
      const float bv = bias[col];
      if (PERMUTE == 2) {
        s16x4 pk;
#pragma unroll
        for (int r = 0; r < 4; ++r) pk[r] = (short)f2bf(acc[mi][ni][r] + bv);
        const int bb = row >> 11, lq = row & (L_ - 1);
        const int hh = col >> 6, e = col & (E_ - 1);
        *(s16x4*)&((u16*)outp)[(((size_t)bb * H_ + hh) * E_ + e) * L_ + lq] = pk;
      } else {
#pragma unroll
        for (int r = 0; r < 4; ++r) {
          const float v = acc[mi][ni][r] + bv;
          const int rr = row + r;
          if (PERMUTE == 1) {
            const int bb = rr >> 11, lq = rr & (L_ - 1);
            const int hh = col >> 6, e = col & (E_ - 1);
            ((u16*)outp)[(((size_t)bb * H_ + hh) * L_ + lq) * E_ + e] = f2bf(v);
          } else {
            ((float*)outp)[(size_t)rr * N + col] = v;
          }
        }
      }
    }
  }
}

// Flash attention, causal. Grid: 1024 blocks (1D). Block: 256 (4 waves x 16 q rows).
// XCD-grouped (xcd = wgid%8 round-robin; XCD c owns bh in [8c,8c+8) -> 4MB L2 set).
// ALL-REGISTER pipeline, zero LDS. K reg-double-buffered; V loaded inside
// process (consumed ~400cy later, covers L2 latency) to keep VGPR <= 128.
__global__ __launch_bounds__(256) void attn_kernel(const u16* __restrict__ qp,
                                                   const u16* __restrict__ kp,
                                                   const u16* __restrict__ vtp,
                                                   u16* __restrict__ op)
{
  const int tid = threadIdx.x;
  const unsigned wgid = blockIdx.x;
  const int bh = (wgid & 7) * 8 + ((wgid >> 3) & 7);   // XCD c -> bh in [8c, 8c+8)
  const int qx = wgid >> 6;                            // 0..15
  const int w = tid >> 6, lane = tid & 63, g = lane >> 4, li = lane & 15;
  const float scl2e = 0.125f * 1.44269504089f;    // (1/sqrt(E)) * log2(e)
  const size_t base  = (size_t)bh * L_ * E_;      // q,k: (B,H,L,E)
  const size_t baseT = (size_t)bh * E_ * L_;      // vt:  (B,H,E,L)
  const int bb = bh >> 4, hh = bh & 15;

  const int qbA = NQT - 1 - qx;                   // 16..31 (long tile)
  const int qbB = qx;                             // 0..15  (short tile)
  const int qbaseA = qbA * 64, qbaseB = qbB * 64;

  const u16* qrA = qp + base + (size_t)(qbaseA + w * 16 + li) * E_;
  const s16x8 qa0A = *(const s16x8*)(qrA + g * 8);
  const s16x8 qa1A = *(const s16x8*)(qrA + 32 + g * 8);
  const u16* qrB = qp + base + (size_t)(qbaseB + w * 16 + li) * E_;
  const s16x8 qa0B = *(const s16x8*)(qrB + g * 8);
  const s16x8 qa1B = *(const s16x8*)(qrB + 32 + g * 8);

  f32x4 oA[4], oB[4];
  float mA = -1e30f, lA = 0.f, mB = -1e30f, lB = 0.f;   // per-lane, q = w*16+li
#pragma unroll
  for (int nc = 0; nc < 4; ++nc) { oA[nc] = (f32x4){0.f,0.f,0.f,0.f}; oB[nc] = (f32x4){0.f,0.f,0.f,0.f}; }

  // permuted K load: A-row li of inst <- K row kvb + 32*(inst>>1)+4*(inst&1)+8*(li>>2)+(li&3)
  const int kro = 8 * (li >> 2) + (li & 3);
  auto loadk = [&](s16x8* kf, int t) {
    const int kvb = t * 64;
#pragma unroll
    for (int inst = 0; inst < 4; ++inst) {
      const u16* kr = kp + base + (size_t)(kvb + 32 * (inst >> 1) + 4 * (inst & 1) + kro) * E_;
      kf[inst * 2]     = *(const s16x8*)(kr + g * 8);
      kf[inst * 2 + 1] = *(const s16x8*)(kr + 32 + g * 8);
    }
  };

  // full attend of one q-tile vs KV tile t; P stays in registers
  auto attend = [&](int t, const s16x8* kf, const s16x8* v0, const s16x8* v1,
                    const s16x8& q0, const s16x8& q1,
                    f32x4* o, float& m_run, float& l_run, int qb, int qbase) {
    float p[4][4];   // [inst][r]: S^T for q=w*16+li, k_local = 32*(inst>>1)+8g+4*(inst&1)+r
#pragma unroll
    for (int inst = 0; inst < 4; ++inst) {
      f32x4 sf = (f32x4){0.f, 0.f, 0.f, 0.f};
      sf = __builtin_amdgcn_mfma_f32_16x16x32_bf16(kf[inst * 2],     q0, sf, 0, 0, 0);
      sf = __builtin_amdgcn_mfma_f32_16x16x32_bf16(kf[inst * 2 + 1], q1, sf, 0, 0, 0);
#pragma unroll
      for (int r = 0; r < 4; ++r) p[inst][r] = sf[r] * scl2e;
    }
    if (t == qb) {   // diagonal tile: causal mask (k > q -> -inf)
      const int qrow = qbase + w * 16 + li;
      const int kvb = t * 64;
#pragma unroll
      for (int inst = 0; inst < 4; ++inst)
#pragma unroll
        for (int r = 0; r < 4; ++r)
          if (kvb + 32 * (inst >> 1) + 8 * g + 4 * (inst & 1) + r > qrow) p[inst][r] = -1e30f;
    }
    // row max: in-register tree + 2 cross-g shfls (row q=li spans g only)
    float m0_ = fmaxf(fmaxf(p[0][0], p[0][1]), fmaxf(p[0][2], p[0][3]));
    float m1_ = fmaxf(fmaxf(p[1][0], p[1][1]), fmaxf(p[1][2], p[1][3]));
    float m2_ = fmaxf(fmaxf(p[2][0], p[2][1]), fmaxf(p[2][2], p[2][3]));
    float m3_ = fmaxf(fmaxf(p[3][0], p[3][1]), fmaxf(p[3][2], p[3][3]));
    float mx = fmaxf(fmaxf(m0_, m1_), fmaxf(m2_, m3_));
    mx = fmaxf(mx, __shfl_xor(mx, 16));
    mx = fmaxf(mx, __shfl_xor(mx, 32));
    const bool resc = __any(mx > m_run + 8.0f);   // defer-max, log2 domain
    if (resc) {
      const float mn = fmaxf(m_run, mx);
      const float alpha = __builtin_amdgcn_exp2f(m_run - mn);
      m_run = mn;
      l_run *= alpha;
#pragma unroll
      for (int nc = 0; nc < 4; ++nc)
#pragma unroll
        for (int r = 0; r < 4; ++r) o[nc][r] *= alpha;   // alpha per-lane (q=li)
    }
    float rs = 0.f;
    unsigned pk[8];
#pragma unroll
    for (int inst = 0; inst < 4; ++inst) {
      const float e0 = __builtin_amdgcn_exp2f(p[inst][0] - m_run);
      const float e1 = __builtin_amdgcn_exp2f(p[inst][1] - m_run);
      const float e2 = __builtin_amdgcn_exp2f(p[inst][2] - m_run);
      const float e3 = __builtin_amdgcn_exp2f(p[inst][3] - m_run);
      rs += (e0 + e1) + (e2 + e3);
      pk[inst * 2]     = pkbf(e0, e1);
      pk[inst * 2 + 1] = pkbf(e2, e3);
    }
    union { s16x8 v; unsigned u[4]; } A0, A1;
    A0.u[0] = pk[0]; A0.u[1] = pk[1]; A0.u[2] = pk[2]; A0.u[3] = pk[3];
    A1.u[0] = pk[4]; A1.u[1] = pk[5]; A1.u[2] = pk[6]; A1.u[3] = pk[7];
    // O^T += V^T * P^T  (v = A-operand, packed P = B-operand)
#pragma unroll
    for (int nc = 0; nc < 4; ++nc) {
      o[nc] = __builtin_amdgcn_mfma_f32_16x16x32_bf16(v0[nc], A0.v, o[nc], 0, 0, 0);
      o[nc] = __builtin_amdgcn_mfma_f32_16x16x32_bf16(v1[nc], A1.v, o[nc], 0, 0, 0);
    }
    rs += __shfl_xor(rs, 16);   // l update off the PV critical path
    rs += __shfl_xor(rs, 32);
    l_run += rs;
  };

  auto process = [&](int t, const s16x8* kf) {
    const int kvb = t * 64;
    s16x8 v0[4], v1[4];   // issued here, consumed after QK+softmax (~400cy)
#pragma unroll
    for (int nc = 0; nc < 4; ++nc) {
      const u16* vrow = vtp + baseT + (size_t)(nc * 16 + li) * L_ + kvb;
      v0[nc] = *(const s16x8*)(vrow + g * 8);
      v1[nc] = *(const s16x8*)(vrow + 32 + g * 8);
    }
    attend(t, kf, v0, v1, qa0A, qa1A, oA, mA, lA, qbA, qbaseA);
    if (t <= qbB) attend(t, kf, v0, v1, qa0B, qa1B, oB, mB, lB, qbB, qbaseB);
  };

  s16x8 kfA[8], kfB[8];
  loadk(kfA, 0);
  for (int t = 0; ; t += 2) {
    if (t + 1 <= qbA) loadk(kfB, t + 1);      // prefetch next tile's K
    process(t, kfA);
    if (t + 1 > qbA) break;
    if (t + 2 <= qbA) loadk(kfA, t + 2);      // prefetch t+2
    process(t + 1, kfB);
    if (t + 2 > qbA) break;
  }

  // O^T epilogue: lane holds O[q=w*16+li][e=nc*16+g*4+r]; stats per-lane.
  auto epilogue = [&](const f32x4* o, float l_run, int qbase) {
    const float inv = 1.0f / l_run;
    u16* orow = op + ((size_t)bb * L_ + qbase + w * 16 + li) * D_ + hh * E_;
#pragma unroll
    for (int nc = 0; nc < 4; ++nc) {
      union { s16x4 v; unsigned u[2]; } P;
      P.u[0] = pkbf(o[nc][0] * inv, o[nc][1] * inv);
      P.u[1] = pkbf(o[nc][2] * inv, o[nc][3] * inv);
      *(s16x4*)&orow[nc * 16 + g * 4] = P.v;
    }
  };
  epilogue(oA, lA, qbaseA);
  epilogue(oB, lB, qbaseB);
}

extern "C" void kernel_launch(void* const* d_in, const int* in_sizes, int n_in,
                              void* d_out, int out_size, void* d_ws, size_t ws_size,
                              hipStream_t stream) {
  const float* queries = (const float*)d_in[0];
  const float* keys    = (const float*)d_in[1];
  const float* values  = (const float*)d_in[2];
  // d_in[3] = attn_mask: exact causal triu(k=1), applied analytically.
  const float* Wq = (const float*)d_in[4];
  const float* bq = (const float*)d_in[5];
  const float* Wk = (const float*)d_in[6];
  const float* bk = (const float*)d_in[7];
  const float* Wv = (const float*)d_in[8];
  const float* bv = (const float*)d_in[9];
  const float* Wo = (const float*)d_in[10];
  const float* bo = (const float*)d_in[11];

  const size_t MD = (size_t)8192 * 1024;
  u16* qbuf = (u16*)d_ws;          // (B,H,L,E) bf16
  u16* kbuf = qbuf + MD;           // (B,H,L,E) bf16
  u16* vbuf = kbuf + MD;           // (B,H,E,L) bf16 (V^T)
  u16* abuf = vbuf + MD;           // attn out (B*L, D) bf16

  dim3 blk(256);
  dim3 ggrid(8, 64);               // (N/128, M/128)
  gemm_bt<0, 1><<<ggrid, blk, 0, stream>>>(queries, Wq, bq, qbuf, 8192, 1024, 1024);
  gemm_bt<0, 1><<<ggrid, blk, 0, stream>>>(keys,    Wk, bk, kbuf, 8192, 1024, 1024);
  gemm_bt<0, 2><<<ggrid, blk, 0, stream>>>(values,  Wv, bv, vbuf, 8192, 1024, 1024);
  attn_kernel<<<dim3(1024), blk, 0, stream>>>(qbuf, kbuf, vbuf, abuf);
  gemm_bt<1, 0><<<ggrid, blk, 0, stream>>>(abuf, Wo, bo, d_out, 8192, 1024, 1024);
}

// Round 11
// 348.559 us; speedup vs baseline: 1.4984x; 1.0019x over previous
//
#include <hip/hip_runtime.h>
#include <hip/hip_bf16.h>

typedef float f32x4 __attribute__((ext_vector_type(4)));
typedef short s16x8 __attribute__((ext_vector_type(8)));
typedef short s16x4 __attribute__((ext_vector_type(4)));
typedef unsigned short u16;

#define H_ 16
#define E_ 64
#define D_ 1024
#define L_ 2048
#define NQT 32   // 64-row q tiles per (b,h)

__device__ __forceinline__ u16 f2bf(float f) {
  union { float f; unsigned u; } v; v.f = f;
  unsigned u = v.u;
  u += 0x7fffu + ((u >> 16) & 1u);   // round-to-nearest-even
  return (u16)(u >> 16);
}

// pack 2 f32 -> 2 bf16 in one u32 (lo=a, hi=b). NON-volatile: schedulable.
__device__ __forceinline__ unsigned pkbf(float a, float b) {
  unsigned r;
  asm("v_cvt_pk_bf16_f32 %0, %1, %2" : "=v"(r) : "v"(a), "v"(b));
  return r;
}

// async global->LDS, 16B per lane. lds base must be wave-uniform; HW adds lane*16.
__device__ __forceinline__ void gld16(const u16* g, u16* l) {
  __builtin_amdgcn_global_load_lds((const __attribute__((address_space(1))) void*)g,
                                   (__attribute__((address_space(3))) void*)l, 16, 0, 0);
}

// f32 -> bf16 bulk convert, 8 elems/thread
__global__ __launch_bounds__(256) void cvtbf(const float* __restrict__ in,
                                             u16* __restrict__ out, int n8) {
  const int i = blockIdx.x * 256 + threadIdx.x;
  if (i < n8) {
    const f32x4 a = *(const f32x4*)(in + (size_t)i * 8);
    const f32x4 b = *(const f32x4*)(in + (size_t)i * 8 + 4);
    s16x8 r;
#pragma unroll
    for (int j = 0; j < 4; ++j) { r[j] = (short)f2bf(a[j]); r[j + 4] = (short)f2bf(b[j]); }
    *(s16x8*)(out + (size_t)i * 8) = r;
  }
}

// ---------- bf16 GEMM, m97 recipe: global_load_lds staging, 2 barriers/iter ----
// out = A (M x K) * W^T + bias. A, W bf16. PERMUTE: 0 = f32 (M x N);
// 1 = bf16 (B,H,L,E); 2 = bf16 (B,H,E,L) (V^T).
template<int PERMUTE>
__global__ __launch_bounds__(256) void gemm_lds(const u16* __restrict__ A,
                                                const u16* __restrict__ W,
                                                const float* __restrict__ bias,
                                                void* __restrict__ outp,
                                                int M, int N, int K)
{
  __shared__ __align__(16) u16 As[128][32];   // 64B rows: 2-way bank alias (free)
  __shared__ __align__(16) u16 Bs[128][32];
  const int tid = threadIdx.x;
  const int m0 = blockIdx.y * 128, n0 = blockIdx.x * 128;
  const int w = tid >> 6, lane = tid & 63, g = lane >> 4, li = lane & 15;
  const int wr = w >> 1, wc = w & 1;
  const int r0 = lane >> 2, cc = (lane & 3) * 8;   // staging row-in-chunk / col

  f32x4 acc[4][4];
#pragma unroll
  for (int i = 0; i < 4; ++i)
#pragma unroll
    for (int j = 0; j < 4; ++j) acc[i][j] = (f32x4){0.f, 0.f, 0.f, 0.f};

  for (int k0 = 0; k0 < K; k0 += 32) {
    // stage 8KB A + 8KB B: wave w owns 1KB chunks {2w, 2w+1} of each
#pragma unroll
    for (int i = 0; i < 2; ++i) {
      const int ch = w * 2 + i;
      const int row = ch * 16 + r0;
      gld16(A + (size_t)(m0 + row) * K + k0 + cc, &As[ch * 16][0]);
      gld16(W + (size_t)(n0 + row) * K + k0 + cc, &Bs[ch * 16][0]);
    }
    __syncthreads();   // waitcnt vmcnt(0) + barrier (compiler-inserted drain)

    s16x8 a[4], b[4];
#pragma unroll
    for (int mi = 0; mi < 4; ++mi) a[mi] = *(const s16x8*)&As[wr * 64 + mi * 16 + li][g * 8];
#pragma unroll
    for (int ni = 0; ni < 4; ++ni) b[ni] = *(const s16x8*)&Bs[wc * 64 + ni * 16 + li][g * 8];
#pragma unroll
    for (int mi = 0; mi < 4; ++mi)
#pragma unroll
      for (int ni = 0; ni < 4; ++ni)
        acc[mi][ni] = __builtin_amdgcn_mfma_f32_16x16x32_bf16(a[mi], b[ni], acc[mi][ni], 0, 0, 0);
    __syncthreads();
  }

#pragma unroll
  for (int mi = 0; mi < 4; ++mi) {
#pragma unroll
    for (int ni = 0; ni < 4; ++ni) {
      const int row = m0 + wr * 64 + mi * 16 + g * 4;
      const int col = n0 + wc * 64 + ni * 16 + li;
      const float bv = bias[col];
      if (PERMUTE == 2) {
        s16x4 pk;
#pragma unroll
        for (int r = 0; r < 4; ++r) pk[r] = (short)f2bf(acc[mi][ni][r] + bv);
        const int bb = row >> 11, lq = row & (L_ - 1);
        const int hh = col >> 6, e = col & (E_ - 1);
        *(s16x4*)&((u16*)outp)[(((size_t)bb * H_ + hh) * E_ + e) * L_ + lq] = pk;
      } else {
#pragma unroll
        for (int r = 0; r < 4; ++r) {
          const float v = acc[mi][ni][r] + bv;
          const int rr = row + r;
          if (PERMUTE == 1) {
            const int bb = rr >> 11, lq = rr & (L_ - 1);
            const int hh = col >> 6, e = col & (E_ - 1);
            ((u16*)outp)[(((size_t)bb * H_ + hh) * L_ + lq) * E_ + e] = f2bf(v);
          } else {
            ((float*)outp)[(size_t)rr * N + col] = v;
          }
        }
      }
    }
  }
}

// ---------- fallback GEMM (R10): reg-staged, f32 A converted on the fly ------
template<int A_BF16, int PERMUTE>
__global__ __launch_bounds__(256) void gemm_bt(const void* __restrict__ Aptr,
                                               const float* __restrict__ W,
                                               const float* __restrict__ bias,
                                               void* __restrict__ outp,
                                               int M, int N, int K)
{
  __shared__ __align__(16) short As[2][128][40];
  __shared__ __align__(16) short Bs[2][128][40];
  const int tid = threadIdx.x;
  const int m0 = blockIdx.y * 128, n0 = blockIdx.x * 128;
  const int w = tid >> 6, lane = tid & 63, g = lane >> 4, li = lane & 15;
  const int wr = w >> 1, wc = w & 1;

  f32x4 acc[4][4];
#pragma unroll
  for (int i = 0; i < 4; ++i)
#pragma unroll
    for (int j = 0; j < 4; ++j) acc[i][j] = (f32x4){0.f, 0.f, 0.f, 0.f};

  f32x4 ra0[2], ra1[2];
  s16x8 rab[2];
  f32x4 rb0[2], rb1[2];

  auto LOAD = [&](int k0) {
#pragma unroll
    for (int p = 0; p < 2; ++p) {
      const int c = p * 256 + tid, row = c >> 2, kc = (c & 3) * 8;
      if (A_BF16) {
        rab[p] = *(const s16x8*)((const u16*)Aptr + (size_t)(m0 + row) * K + k0 + kc);
      } else {
        const float* ap = (const float*)Aptr + (size_t)(m0 + row) * K + k0 + kc;
        ra0[p] = *(const f32x4*)ap; ra1[p] = *(const f32x4*)(ap + 4);
      }
      const float* wp = W + (size_t)(n0 + row) * K + k0 + kc;
      rb0[p] = *(const f32x4*)wp; rb1[p] = *(const f32x4*)(wp + 4);
    }
  };
  auto WRITE = [&](int buf) {
#pragma unroll
    for (int p = 0; p < 2; ++p) {
      const int c = p * 256 + tid, row = c >> 2, kc = (c & 3) * 8;
      if (A_BF16) {
        *(s16x8*)&As[buf][row][kc] = rab[p];
      } else {
        s16x8 r;
#pragma unroll
        for (int j = 0; j < 4; ++j) { r[j] = (short)f2bf(ra0[p][j]); r[j + 4] = (short)f2bf(ra1[p][j]); }
        *(s16x8*)&As[buf][row][kc] = r;
      }
      s16x8 rb;
#pragma unroll
      for (int j = 0; j < 4; ++j) { rb[j] = (short)f2bf(rb0[p][j]); rb[j + 4] = (short)f2bf(rb1[p][j]); }
      *(s16x8*)&Bs[buf][row][kc] = rb;
    }
  };

  LOAD(0); WRITE(0);
  __syncthreads();
  int cur = 0;
  for (int k0 = 0; k0 < K; k0 += 32) {
    const bool more = (k0 + 32 < K);
    if (more) LOAD(k0 + 32);

    s16x8 a[4], b[4];
#pragma unroll
    for (int mi = 0; mi < 4; ++mi) a[mi] = *(const s16x8*)&As[cur][wr * 64 + mi * 16 + li][g * 8];
#pragma unroll
    for (int ni = 0; ni < 4; ++ni) b[ni] = *(const s16x8*)&Bs[cur][wc * 64 + ni * 16 + li][g * 8];
#pragma unroll
    for (int mi = 0; mi < 4; ++mi)
#pragma unroll
      for (int ni = 0; ni < 4; ++ni)
        acc[mi][ni] = __builtin_amdgcn_mfma_f32_16x16x32_bf16(a[mi], b[ni], acc[mi][ni], 0, 0, 0);

    if (more) { WRITE(cur ^ 1); __syncthreads(); }
    cur ^= 1;
  }

#pragma unroll
  for (int mi = 0; mi < 4; ++mi) {
#pragma unroll
    for (int ni = 0; ni < 4; ++ni) {
      const int row = m0 + wr * 64 + mi * 16 + g * 4;
      const int col = n0 + wc * 64 + ni * 16 + li;
      const float bv = bias[col];
      if (PERMUTE == 2) {
        s16x4 pk;
#pragma unroll
        for (int r = 0; r < 4; ++r) pk[r] = (short)f2bf(acc[mi][ni][r] + bv);
        const int bb = row >> 11, lq = row & (L_ - 1);
        const int hh = col >> 6, e = col & (E_ - 1);
        *(s16x4*)&((u16*)outp)[(((size_t)bb * H_ + hh) * E_ + e) * L_ + lq] = pk;
      } else {
#pragma unroll
        for (int r = 0; r < 4; ++r) {
          const float v = acc[mi][ni][r] + bv;
          const int rr = row + r;
          if (PERMUTE == 1) {
            const int bb = rr >> 11, lq = rr & (L_ - 1);
            const int hh = col >> 6, e = col & (E_ - 1);
            ((u16*)outp)[(((size_t)bb * H_ + hh) * L_ + lq) * E_ + e] = f2bf(v);
          } else {
            ((float*)outp)[(size_t)rr * N + col] = v;
          }
        }
      }
    }
  }
}

// Flash attention, causal. Grid: 1024 (1D). Block: 256 (4 waves x 16 q rows).
// XCD-grouped (xcd=wgid%8; XCD c owns bh in [8c,8c+8) -> 4MB L2 set).
// ALL-REGISTER, zero LDS. ORDER FIX vs R10: V(t) issued BEFORE K(t+1) prefetch,
// so PV's waitcnt is vmcnt(8) and the K prefetch stays in flight across tiles.
__global__ __launch_bounds__(256) void attn_kernel(const u16* __restrict__ qp,
                                                   const u16* __restrict__ kp,
                                                   const u16* __restrict__ vtp,
                                                   u16* __restrict__ op)
{
  const int tid = threadIdx.x;
  const unsigned wgid = blockIdx.x;
  const int bh = (wgid & 7) * 8 + ((wgid >> 3) & 7);
  const int qx = wgid >> 6;
  const int w = tid >> 6, lane = tid & 63, g = lane >> 4, li = lane & 15;
  const float scl2e = 0.125f * 1.44269504089f;
  const size_t base  = (size_t)bh * L_ * E_;
  const size_t baseT = (size_t)bh * E_ * L_;
  const int bb = bh >> 4, hh = bh & 15;

  const int qbA = NQT - 1 - qx;
  const int qbB = qx;
  const int qbaseA = qbA * 64, qbaseB = qbB * 64;

  const u16* qrA = qp + base + (size_t)(qbaseA + w * 16 + li) * E_;
  const s16x8 qa0A = *(const s16x8*)(qrA + g * 8);
  const s16x8 qa1A = *(const s16x8*)(qrA + 32 + g * 8);
  const u16* qrB = qp + base + (size_t)(qbaseB + w * 16 + li) * E_;
  const s16x8 qa0B = *(const s16x8*)(qrB + g * 8);
  const s16x8 qa1B = *(const s16x8*)(qrB + 32 + g * 8);

  f32x4 oA[4], oB[4];
  float mA = -1e30f, lA = 0.f, mB = -1e30f, lB = 0.f;
#pragma unroll
  for (int nc = 0; nc < 4; ++nc) { oA[nc] = (f32x4){0.f,0.f,0.f,0.f}; oB[nc] = (f32x4){0.f,0.f,0.f,0.f}; }

  const int kro = 8 * (li >> 2) + (li & 3);
  auto loadk = [&](s16x8* kf, int t) {
    const int kvb = t * 64;
#pragma unroll
    for (int inst = 0; inst < 4; ++inst) {
      const u16* kr = kp + base + (size_t)(kvb + 32 * (inst >> 1) + 4 * (inst & 1) + kro) * E_;
      kf[inst * 2]     = *(const s16x8*)(kr + g * 8);
      kf[inst * 2 + 1] = *(const s16x8*)(kr + 32 + g * 8);
    }
  };

  auto attend = [&](int t, const s16x8* kf, const s16x8* v0, const s16x8* v1,
                    const s16x8& q0, const s16x8& q1,
                    f32x4* o, float& m_run, float& l_run, int qb, int qbase) {
    float p[4][4];
#pragma unroll
    for (int inst = 0; inst < 4; ++inst) {
      f32x4 sf = (f32x4){0.f, 0.f, 0.f, 0.f};
      sf = __builtin_amdgcn_mfma_f32_16x16x32_bf16(kf[inst * 2],     q0, sf, 0, 0, 0);
      sf = __builtin_amdgcn_mfma_f32_16x16x32_bf16(kf[inst * 2 + 1], q1, sf, 0, 0, 0);
#pragma unroll
      for (int r = 0; r < 4; ++r) p[inst][r] = sf[r] * scl2e;
    }
    if (t == qb) {
      const int qrow = qbase + w * 16 + li;
      const int kvb = t * 64;
#pragma unroll
      for (int inst = 0; inst < 4; ++inst)
#pragma unroll
        for (int r = 0; r < 4; ++r)
          if (kvb + 32 * (inst >> 1) + 8 * g + 4 * (inst & 1) + r > qrow) p[inst][r] = -1e30f;
    }
    float m0_ = fmaxf(fmaxf(p[0][0], p[0][1]), fmaxf(p[0][2], p[0][3]));
    float m1_ = fmaxf(fmaxf(p[1][0], p[1][1]), fmaxf(p[1][2], p[1][3]));
    float m2_ = fmaxf(fmaxf(p[2][0], p[2][1]), fmaxf(p[2][2], p[2][3]));
    float m3_ = fmaxf(fmaxf(p[3][0], p[3][1]), fmaxf(p[3][2], p[3][3]));
    float mx = fmaxf(fmaxf(m0_, m1_), fmaxf(m2_, m3_));
    mx = fmaxf(mx, __shfl_xor(mx, 16));
    mx = fmaxf(mx, __shfl_xor(mx, 32));
    const bool resc = __any(mx > m_run + 8.0f);
    if (resc) {
      const float mn = fmaxf(m_run, mx);
      const float alpha = __builtin_amdgcn_exp2f(m_run - mn);
      m_run = mn;
      l_run *= alpha;
#pragma unroll
      for (int nc = 0; nc < 4; ++nc)
#pragma unroll
        for (int r = 0; r < 4; ++r) o[nc][r] *= alpha;
    }
    float rs = 0.f;
    unsigned pk[8];
#pragma unroll
    for (int inst = 0; inst < 4; ++inst) {
      const float e0 = __builtin_amdgcn_exp2f(p[inst][0] - m_run);
      const float e1 = __builtin_amdgcn_exp2f(p[inst][1] - m_run);
      const float e2 = __builtin_amdgcn_exp2f(p[inst][2] - m_run);
      const float e3 = __builtin_amdgcn_exp2f(p[inst][3] - m_run);
      rs += (e0 + e1) + (e2 + e3);
      pk[inst * 2]     = pkbf(e0, e1);
      pk[inst * 2 + 1] = pkbf(e2, e3);
    }
    union { s16x8 v; unsigned u[4]; } A0, A1;
    A0.u[0] = pk[0]; A0.u[1] = pk[1]; A0.u[2] = pk[2]; A0.u[3] = pk[3];
    A1.u[0] = pk[4]; A1.u[1] = pk[5]; A1.u[2] = pk[6]; A1.u[3] = pk[7];
#pragma unroll
    for (int nc = 0; nc < 4; ++nc) {
      o[nc] = __builtin_amdgcn_mfma_f32_16x16x32_bf16(v0[nc], A0.v, o[nc], 0, 0, 0);
      o[nc] = __builtin_amdgcn_mfma_f32_16x16x32_bf16(v1[nc], A1.v, o[nc], 0, 0, 0);
    }
    rs += __shfl_xor(rs, 16);
    rs += __shfl_xor(rs, 32);
    l_run += rs;
  };

  auto step = [&](int t, const s16x8* kf, s16x8* kfn) {
    const int kvb = t * 64;
    s16x8 v0[4], v1[4];
#pragma unroll
    for (int nc = 0; nc < 4; ++nc) {         // V FIRST (oldest vmcnt slots)
      const u16* vrow = vtp + baseT + (size_t)(nc * 16 + li) * L_ + kvb;
      v0[nc] = *(const s16x8*)(vrow + g * 8);
      v1[nc] = *(const s16x8*)(vrow + 32 + g * 8);
    }
    if (t + 1 <= qbA) loadk(kfn, t + 1);     // prefetch stays in flight past PV
    attend(t, kf, v0, v1, qa0A, qa1A, oA, mA, lA, qbA, qbaseA);
    if (t <= qbB) attend(t, kf, v0, v1, qa0B, qa1B, oB, mB, lB, qbB, qbaseB);
  };

  s16x8 kfA[8], kfB[8];
  loadk(kfA, 0);
  for (int t = 0; ; t += 2) {
    step(t, kfA, kfB);
    if (t + 1 > qbA) break;
    step(t + 1, kfB, kfA);
    if (t + 2 > qbA) break;
  }

  auto epilogue = [&](const f32x4* o, float l_run, int qbase) {
    const float inv = 1.0f / l_run;
    u16* orow = op + ((size_t)bb * L_ + qbase + w * 16 + li) * D_ + hh * E_;
#pragma unroll
    for (int nc = 0; nc < 4; ++nc) {
      union { s16x4 v; unsigned u[2]; } P;
      P.u[0] = pkbf(o[nc][0] * inv, o[nc][1] * inv);
      P.u[1] = pkbf(o[nc][2] * inv, o[nc][3] * inv);
      *(s16x4*)&orow[nc * 16 + g * 4] = P.v;
    }
  };
  epilogue(oA, lA, qbaseA);
  epilogue(oB, lB, qbaseB);
}

extern "C" void kernel_launch(void* const* d_in, const int* in_sizes, int n_in,
                              void* d_out, int out_size, void* d_ws, size_t ws_size,
                              hipStream_t stream) {
  const float* queries = (const float*)d_in[0];
  const float* keys    = (const float*)d_in[1];
  const float* values  = (const float*)d_in[2];
  // d_in[3] = attn_mask: exact causal triu(k=1), applied analytically.
  const float* Wq = (const float*)d_in[4];
  const float* bq = (const float*)d_in[5];
  const float* Wk = (const float*)d_in[6];
  const float* bk = (const float*)d_in[7];
  const float* Wv = (const float*)d_in[8];
  const float* bv = (const float*)d_in[9];
  const float* Wo = (const float*)d_in[10];
  const float* bo = (const float*)d_in[11];

  const size_t MD = (size_t)8192 * 1024;   // activation elems
  const size_t WN = (size_t)1024 * 1024;   // weight elems
  u16* qbuf = (u16*)d_ws;
  u16* kbuf = qbuf + MD;
  u16* vbuf = kbuf + MD;
  u16* abuf = vbuf + MD;

  dim3 blk(256);
  dim3 ggrid(8, 64);

  const size_t need = (4 * MD + 4 * WN) * sizeof(u16);
  if (ws_size >= need) {
    // bf16 path: pre-convert; aliases consumed in order V -> K -> Q -> attn.
    u16* qcv = abuf;           // overwritten by attn (after Q-GEMM reads it)
    u16* kcv = qbuf;           // overwritten by Q-GEMM (after K-GEMM reads it)
    u16* vcv = kbuf;           // overwritten by K-GEMM (after V-GEMM reads it)
    u16* wqb = abuf + MD;
    u16* wkb = wqb + WN;
    u16* wvb = wkb + WN;
    u16* wob = wvb + WN;

    cvtbf<<<dim3(4096), blk, 0, stream>>>(queries, qcv, (int)(MD / 8));
    cvtbf<<<dim3(4096), blk, 0, stream>>>(keys,    kcv, (int)(MD / 8));
    cvtbf<<<dim3(4096), blk, 0, stream>>>(values,  vcv, (int)(MD / 8));
    cvtbf<<<dim3(512),  blk, 0, stream>>>(Wq, wqb, (int)(WN / 8));
    cvtbf<<<dim3(512),  blk, 0, stream>>>(Wk, wkb, (int)(WN / 8));
    cvtbf<<<dim3(512),  blk, 0, stream>>>(Wv, wvb, (int)(WN / 8));
    cvtbf<<<dim3(512),  blk, 0, stream>>>(Wo, wob, (int)(WN / 8));

    gemm_lds<2><<<ggrid, blk, 0, stream>>>(vcv, wvb, bv, vbuf, 8192, 1024, 1024);
    gemm_lds<1><<<ggrid, blk, 0, stream>>>(kcv, wkb, bk, kbuf, 8192, 1024, 1024);
    gemm_lds<1><<<ggrid, blk, 0, stream>>>(qcv, wqb, bq, qbuf, 8192, 1024, 1024);
    attn_kernel<<<dim3(1024), blk, 0, stream>>>(qbuf, kbuf, vbuf, abuf);
    gemm_lds<0><<<ggrid, blk, 0, stream>>>(abuf, wob, bo, d_out, 8192, 1024, 1024);
  } else {
    // fallback: R10 path (reg-staged GEMM, f32 A converted on the fly)
    gemm_bt<0, 1><<<ggrid, blk, 0, stream>>>(queries, Wq, bq, qbuf, 8192, 1024, 1024);
    gemm_bt<0, 1><<<ggrid, blk, 0, stream>>>(keys,    Wk, bk, kbuf, 8192, 1024, 1024);
    gemm_bt<0, 2><<<ggrid, blk, 0, stream>>>(values,  Wv, bv, vbuf, 8192, 1024, 1024);
    attn_kernel<<<dim3(1024), blk, 0, stream>>>(qbuf, kbuf, vbuf, abuf);
    gemm_bt<1, 0><<<ggrid, blk, 0, stream>>>(abuf, Wo, bo, d_out, 8192, 1024, 1024);
  }
}

// Round 12
// 345.313 us; speedup vs baseline: 1.5125x; 1.0094x over previous
//
#include <hip/hip_runtime.h>
#include <hip/hip_bf16.h>

typedef float f32x4 __attribute__((ext_vector_type(4)));
typedef short s16x8 __attribute__((ext_vector_type(8)));
typedef short s16x4 __attribute__((ext_vector_type(4)));
typedef unsigned short u16;

#define H_ 16
#define E_ 64
#define D_ 1024
#define L_ 2048
#define NQT 32   // 64-row q tiles per (b,h)

__device__ __forceinline__ u16 f2bf(float f) {
  union { float f; unsigned u; } v; v.f = f;
  unsigned u = v.u;
  u += 0x7fffu + ((u >> 16) & 1u);   // round-to-nearest-even
  return (u16)(u >> 16);
}

// pack 2 f32 -> 2 bf16 in one u32 (lo=a, hi=b). NON-volatile: schedulable.
__device__ __forceinline__ unsigned pkbf(float a, float b) {
  unsigned r;
  asm("v_cvt_pk_bf16_f32 %0, %1, %2" : "=v"(r) : "v"(a), "v"(b));
  return r;
}

// async global->LDS, 16B per lane. lds base must be wave-uniform; HW adds lane*16.
__device__ __forceinline__ void gld16(const u16* g, u16* l) {
  __builtin_amdgcn_global_load_lds((const __attribute__((address_space(1))) void*)g,
                                   (__attribute__((address_space(3))) void*)l, 16, 0, 0);
}

// f32 -> bf16 bulk convert, 8 elems/thread
__global__ __launch_bounds__(256) void cvtbf(const float* __restrict__ in,
                                             u16* __restrict__ out, int n8) {
  const int i = blockIdx.x * 256 + threadIdx.x;
  if (i < n8) {
    const f32x4 a = *(const f32x4*)(in + (size_t)i * 8);
    const f32x4 b = *(const f32x4*)(in + (size_t)i * 8 + 4);
    s16x8 r;
#pragma unroll
    for (int j = 0; j < 4; ++j) { r[j] = (short)f2bf(a[j]); r[j + 4] = (short)f2bf(b[j]); }
    *(s16x8*)(out + (size_t)i * 8) = r;
  }
}

// ---------- bf16 GEMM, m97 recipe: global_load_lds staging, 2 barriers/iter ----
template<int PERMUTE>
__global__ __launch_bounds__(256) void gemm_lds(const u16* __restrict__ A,
                                                const u16* __restrict__ W,
                                                const float* __restrict__ bias,
                                                void* __restrict__ outp,
                                                int M, int N, int K)
{
  __shared__ __align__(16) u16 As[128][32];   // 64B rows: 2-way bank alias (free)
  __shared__ __align__(16) u16 Bs[128][32];
  const int tid = threadIdx.x;
  const int m0 = blockIdx.y * 128, n0 = blockIdx.x * 128;
  const int w = tid >> 6, lane = tid & 63, g = lane >> 4, li = lane & 15;
  const int wr = w >> 1, wc = w & 1;
  const int r0 = lane >> 2, cc = (lane & 3) * 8;

  f32x4 acc[4][4];
#pragma unroll
  for (int i = 0; i < 4; ++i)
#pragma unroll
    for (int j = 0; j < 4; ++j) acc[i][j] = (f32x4){0.f, 0.f, 0.f, 0.f};

  for (int k0 = 0; k0 < K; k0 += 32) {
#pragma unroll
    for (int i = 0; i < 2; ++i) {
      const int ch = w * 2 + i;
      const int row = ch * 16 + r0;
      gld16(A + (size_t)(m0 + row) * K + k0 + cc, &As[ch * 16][0]);
      gld16(W + (size_t)(n0 + row) * K + k0 + cc, &Bs[ch * 16][0]);
    }
    __syncthreads();

    s16x8 a[4], b[4];
#pragma unroll
    for (int mi = 0; mi < 4; ++mi) a[mi] = *(const s16x8*)&As[wr * 64 + mi * 16 + li][g * 8];
#pragma unroll
    for (int ni = 0; ni < 4; ++ni) b[ni] = *(const s16x8*)&Bs[wc * 64 + ni * 16 + li][g * 8];
#pragma unroll
    for (int mi = 0; mi < 4; ++mi)
#pragma unroll
      for (int ni = 0; ni < 4; ++ni)
        acc[mi][ni] = __builtin_amdgcn_mfma_f32_16x16x32_bf16(a[mi], b[ni], acc[mi][ni], 0, 0, 0);
    __syncthreads();
  }

#pragma unroll
  for (int mi = 0; mi < 4; ++mi) {
#pragma unroll
    for (int ni = 0; ni < 4; ++ni) {
      const int row = m0 + wr * 64 + mi * 16 + g * 4;
      const int col = n0 + wc * 64 + ni * 16 + li;
      const float bv = bias[col];
      if (PERMUTE == 2) {
        s16x4 pk;
#pragma unroll
        for (int r = 0; r < 4; ++r) pk[r] = (short)f2bf(acc[mi][ni][r] + bv);
        const int bb = row >> 11, lq = row & (L_ - 1);
        const int hh = col >> 6, e = col & (E_ - 1);
        *(s16x4*)&((u16*)outp)[(((size_t)bb * H_ + hh) * E_ + e) * L_ + lq] = pk;
      } else {
#pragma unroll
        for (int r = 0; r < 4; ++r) {
          const float v = acc[mi][ni][r] + bv;
          const int rr = row + r;
          if (PERMUTE == 1) {
            const int bb = rr >> 11, lq = rr & (L_ - 1);
            const int hh = col >> 6, e = col & (E_ - 1);
            ((u16*)outp)[(((size_t)bb * H_ + hh) * L_ + lq) * E_ + e] = f2bf(v);
          } else {
            ((float*)outp)[(size_t)rr * N + col] = v;
          }
        }
      }
    }
  }
}

// ---------- fallback GEMM (reg-staged, f32 A converted on the fly) ------------
template<int A_BF16, int PERMUTE>
__global__ __launch_bounds__(256) void gemm_bt(const void* __restrict__ Aptr,
                                               const float* __restrict__ W,
                                               const float* __restrict__ bias,
                                               void* __restrict__ outp,
                                               int M, int N, int K)
{
  __shared__ __align__(16) short As[2][128][40];
  __shared__ __align__(16) short Bs[2][128][40];
  const int tid = threadIdx.x;
  const int m0 = blockIdx.y * 128, n0 = blockIdx.x * 128;
  const int w = tid >> 6, lane = tid & 63, g = lane >> 4, li = lane & 15;
  const int wr = w >> 1, wc = w & 1;

  f32x4 acc[4][4];
#pragma unroll
  for (int i = 0; i < 4; ++i)
#pragma unroll
    for (int j = 0; j < 4; ++j) acc[i][j] = (f32x4){0.f, 0.f, 0.f, 0.f};

  f32x4 ra0[2], ra1[2];
  s16x8 rab[2];
  f32x4 rb0[2], rb1[2];

  auto LOAD = [&](int k0) {
#pragma unroll
    for (int p = 0; p < 2; ++p) {
      const int c = p * 256 + tid, row = c >> 2, kc = (c & 3) * 8;
      if (A_BF16) {
        rab[p] = *(const s16x8*)((const u16*)Aptr + (size_t)(m0 + row) * K + k0 + kc);
      } else {
        const float* ap = (const float*)Aptr + (size_t)(m0 + row) * K + k0 + kc;
        ra0[p] = *(const f32x4*)ap; ra1[p] = *(const f32x4*)(ap + 4);
      }
      const float* wp = W + (size_t)(n0 + row) * K + k0 + kc;
      rb0[p] = *(const f32x4*)wp; rb1[p] = *(const f32x4*)(wp + 4);
    }
  };
  auto WRITE = [&](int buf) {
#pragma unroll
    for (int p = 0; p < 2; ++p) {
      const int c = p * 256 + tid, row = c >> 2, kc = (c & 3) * 8;
      if (A_BF16) {
        *(s16x8*)&As[buf][row][kc] = rab[p];
      } else {
        s16x8 r;
#pragma unroll
        for (int j = 0; j < 4; ++j) { r[j] = (short)f2bf(ra0[p][j]); r[j + 4] = (short)f2bf(ra1[p][j]); }
        *(s16x8*)&As[buf][row][kc] = r;
      }
      s16x8 rb;
#pragma unroll
      for (int j = 0; j < 4; ++j) { rb[j] = (short)f2bf(rb0[p][j]); rb[j + 4] = (short)f2bf(rb1[p][j]); }
      *(s16x8*)&Bs[buf][row][kc] = rb;
    }
  };

  LOAD(0); WRITE(0);
  __syncthreads();
  int cur = 0;
  for (int k0 = 0; k0 < K; k0 += 32) {
    const bool more = (k0 + 32 < K);
    if (more) LOAD(k0 + 32);

    s16x8 a[4], b[4];
#pragma unroll
    for (int mi = 0; mi < 4; ++mi) a[mi] = *(const s16x8*)&As[cur][wr * 64 + mi * 16 + li][g * 8];
#pragma unroll
    for (int ni = 0; ni < 4; ++ni) b[ni] = *(const s16x8*)&Bs[cur][wc * 64 + ni * 16 + li][g * 8];
#pragma unroll
    for (int mi = 0; mi < 4; ++mi)
#pragma unroll
      for (int ni = 0; ni < 4; ++ni)
        acc[mi][ni] = __builtin_amdgcn_mfma_f32_16x16x32_bf16(a[mi], b[ni], acc[mi][ni], 0, 0, 0);

    if (more) { WRITE(cur ^ 1); __syncthreads(); }
    cur ^= 1;
  }

#pragma unroll
  for (int mi = 0; mi < 4; ++mi) {
#pragma unroll
    for (int ni = 0; ni < 4; ++ni) {
      const int row = m0 + wr * 64 + mi * 16 + g * 4;
      const int col = n0 + wc * 64 + ni * 16 + li;
      const float bv = bias[col];
      if (PERMUTE == 2) {
        s16x4 pk;
#pragma unroll
        for (int r = 0; r < 4; ++r) pk[r] = (short)f2bf(acc[mi][ni][r] + bv);
        const int bb = row >> 11, lq = row & (L_ - 1);
        const int hh = col >> 6, e = col & (E_ - 1);
        *(s16x4*)&((u16*)outp)[(((size_t)bb * H_ + hh) * E_ + e) * L_ + lq] = pk;
      } else {
#pragma unroll
        for (int r = 0; r < 4; ++r) {
          const float v = acc[mi][ni][r] + bv;
          const int rr = row + r;
          if (PERMUTE == 1) {
            const int bb = rr >> 11, lq = rr & (L_ - 1);
            const int hh = col >> 6, e = col & (E_ - 1);
            ((u16*)outp)[(((size_t)bb * H_ + hh) * L_ + lq) * E_ + e] = f2bf(v);
          } else {
            ((float*)outp)[(size_t)rr * N + col] = v;
          }
        }
      }
    }
  }
}

// Flash attention, causal. Grid: 1024 (1D). Block: 256 (4 waves x 16 q rows).
// XCD-grouped; ALL-REGISTER; T15 double-pipeline: QK(t+1) is computed BETWEEN
// softmax(t) and PV(t), writing the p registers softmax just freed. softmax(t+1)
// therefore has a full iteration of slack behind its QK. Single kf/v buffers
// (loaded and consumed within one iteration).
__global__ __launch_bounds__(256) void attn_kernel(const u16* __restrict__ qp,
                                                   const u16* __restrict__ kp,
                                                   const u16* __restrict__ vtp,
                                                   u16* __restrict__ op)
{
  const int tid = threadIdx.x;
  const unsigned wgid = blockIdx.x;
  const int bh = (wgid & 7) * 8 + ((wgid >> 3) & 7);   // XCD c owns bh in [8c,8c+8)
  const int qx = wgid >> 6;
  const int w = tid >> 6, lane = tid & 63, g = lane >> 4, li = lane & 15;
  const float scl2e = 0.125f * 1.44269504089f;
  const size_t base  = (size_t)bh * L_ * E_;
  const size_t baseT = (size_t)bh * E_ * L_;
  const int bb = bh >> 4, hh = bh & 15;

  const int qbA = NQT - 1 - qx;
  const int qbB = qx;
  const int qbaseA = qbA * 64, qbaseB = qbB * 64;

  const u16* qrA = qp + base + (size_t)(qbaseA + w * 16 + li) * E_;
  const s16x8 qa0A = *(const s16x8*)(qrA + g * 8);
  const s16x8 qa1A = *(const s16x8*)(qrA + 32 + g * 8);
  const u16* qrB = qp + base + (size_t)(qbaseB + w * 16 + li) * E_;
  const s16x8 qa0B = *(const s16x8*)(qrB + g * 8);
  const s16x8 qa1B = *(const s16x8*)(qrB + 32 + g * 8);

  f32x4 oA[4], oB[4];
  float mA = -1e30f, lA = 0.f, mB = -1e30f, lB = 0.f;
#pragma unroll
  for (int nc = 0; nc < 4; ++nc) { oA[nc] = (f32x4){0.f,0.f,0.f,0.f}; oB[nc] = (f32x4){0.f,0.f,0.f,0.f}; }

  s16x8 kf[8];          // single buffer: loaded + consumed within one iteration
  s16x8 v0[4], v1[4];
  f32x4 pA[4], pB[4];   // pre-exp scores (log2 domain), one tile ahead

  const int kro = 8 * (li >> 2) + (li & 3);
  auto loadk = [&](int t) {
    const int kvb = t * 64;
#pragma unroll
    for (int inst = 0; inst < 4; ++inst) {
      const u16* kr = kp + base + (size_t)(kvb + 32 * (inst >> 1) + 4 * (inst & 1) + kro) * E_;
      kf[inst * 2]     = *(const s16x8*)(kr + g * 8);
      kf[inst * 2 + 1] = *(const s16x8*)(kr + 32 + g * 8);
    }
  };
  auto loadv = [&](int t) {
    const int kvb = t * 64;
#pragma unroll
    for (int nc = 0; nc < 4; ++nc) {
      const u16* vrow = vtp + baseT + (size_t)(nc * 16 + li) * L_ + kvb;
      v0[nc] = *(const s16x8*)(vrow + g * 8);
      v1[nc] = *(const s16x8*)(vrow + 32 + g * 8);
    }
  };
  // QK for tile t into p (scaled, masked if diagonal)
  auto qk = [&](const s16x8& q0, const s16x8& q1, f32x4* p, int t, int qb, int qbase) {
#pragma unroll
    for (int inst = 0; inst < 4; ++inst) {
      f32x4 sf = (f32x4){0.f, 0.f, 0.f, 0.f};
      sf = __builtin_amdgcn_mfma_f32_16x16x32_bf16(kf[inst * 2],     q0, sf, 0, 0, 0);
      sf = __builtin_amdgcn_mfma_f32_16x16x32_bf16(kf[inst * 2 + 1], q1, sf, 0, 0, 0);
#pragma unroll
      for (int r = 0; r < 4; ++r) p[inst][r] = sf[r] * scl2e;
    }
    if (t == qb) {
      const int qrow = qbase + w * 16 + li;
      const int kvb = t * 64;
#pragma unroll
      for (int inst = 0; inst < 4; ++inst)
#pragma unroll
        for (int r = 0; r < 4; ++r)
          if (kvb + 32 * (inst >> 1) + 8 * g + 4 * (inst & 1) + r > qrow) p[inst][r] = -1e30f;
    }
  };
  // softmax: consumes p, produces pk[8] + partial row-sum (reduced later)
  auto sm = [&](f32x4* p, float& m_run, float& l_run, f32x4* o, unsigned* pk) -> float {
    float m0_ = fmaxf(fmaxf(p[0][0], p[0][1]), fmaxf(p[0][2], p[0][3]));
    float m1_ = fmaxf(fmaxf(p[1][0], p[1][1]), fmaxf(p[1][2], p[1][3]));
    float m2_ = fmaxf(fmaxf(p[2][0], p[2][1]), fmaxf(p[2][2], p[2][3]));
    float m3_ = fmaxf(fmaxf(p[3][0], p[3][1]), fmaxf(p[3][2], p[3][3]));
    float mx = fmaxf(fmaxf(m0_, m1_), fmaxf(m2_, m3_));
    mx = fmaxf(mx, __shfl_xor(mx, 16));
    mx = fmaxf(mx, __shfl_xor(mx, 32));
    const bool resc = __any(mx > m_run + 8.0f);   // defer-max (log2 domain)
    if (resc) {
      const float mn = fmaxf(m_run, mx);
      const float alpha = __builtin_amdgcn_exp2f(m_run - mn);
      m_run = mn;
      l_run *= alpha;
#pragma unroll
      for (int nc = 0; nc < 4; ++nc)
#pragma unroll
        for (int r = 0; r < 4; ++r) o[nc][r] *= alpha;
    }
    float rs = 0.f;
#pragma unroll
    for (int inst = 0; inst < 4; ++inst) {
      const float e0 = __builtin_amdgcn_exp2f(p[inst][0] - m_run);
      const float e1 = __builtin_amdgcn_exp2f(p[inst][1] - m_run);
      const float e2 = __builtin_amdgcn_exp2f(p[inst][2] - m_run);
      const float e3 = __builtin_amdgcn_exp2f(p[inst][3] - m_run);
      rs += (e0 + e1) + (e2 + e3);
      pk[inst * 2]     = pkbf(e0, e1);
      pk[inst * 2 + 1] = pkbf(e2, e3);
    }
    return rs;
  };
  auto pv = [&](const unsigned* pk, f32x4* o) {
    union { s16x8 v; unsigned u[4]; } A0, A1;
    A0.u[0] = pk[0]; A0.u[1] = pk[1]; A0.u[2] = pk[2]; A0.u[3] = pk[3];
    A1.u[0] = pk[4]; A1.u[1] = pk[5]; A1.u[2] = pk[6]; A1.u[3] = pk[7];
#pragma unroll
    for (int nc = 0; nc < 4; ++nc) {
      o[nc] = __builtin_amdgcn_mfma_f32_16x16x32_bf16(v0[nc], A0.v, o[nc], 0, 0, 0);
      o[nc] = __builtin_amdgcn_mfma_f32_16x16x32_bf16(v1[nc], A1.v, o[nc], 0, 0, 0);
    }
  };

  // prologue: K(0) + QK(0) for both chains
  loadk(0);
  qk(qa0A, qa1A, pA, 0, qbA, qbaseA);
  qk(qa0B, qa1B, pB, 0, qbB, qbaseB);

  unsigned pkA[8], pkB[8];
  for (int t = 0; t <= qbA; ++t) {
    loadv(t);                                  // V(t): oldest vmcnt slots
    const bool more  = (t + 1 <= qbA);
    const bool doB   = (t     <= qbB);
    const bool moreB = (t + 1 <= qbB);
    if (more) loadk(t + 1);                    // K(t+1): in flight during softmax

    float rsA = sm(pA, mA, lA, oA, pkA);       // consumes pA -> pA free
    float rsB = 0.f;
    if (doB) rsB = sm(pB, mB, lB, oB, pkB);

    if (more)  qk(qa0A, qa1A, pA, t + 1, qbA, qbaseA);   // QK(t+1) fills stall
    if (moreB) qk(qa0B, qa1B, pB, t + 1, qbB, qbaseB);

    pv(pkA, oA);                               // v arrived (older than kf)
    if (doB) pv(pkB, oB);

    rsA += __shfl_xor(rsA, 16); rsA += __shfl_xor(rsA, 32);
    lA += rsA;
    if (doB) { rsB += __shfl_xor(rsB, 16); rsB += __shfl_xor(rsB, 32); lB += rsB; }
  }

  auto epilogue = [&](const f32x4* o, float l_run, int qbase) {
    const float inv = 1.0f / l_run;
    u16* orow = op + ((size_t)bb * L_ + qbase + w * 16 + li) * D_ + hh * E_;
#pragma unroll
    for (int nc = 0; nc < 4; ++nc) {
      union { s16x4 v; unsigned u[2]; } P;
      P.u[0] = pkbf(o[nc][0] * inv, o[nc][1] * inv);
      P.u[1] = pkbf(o[nc][2] * inv, o[nc][3] * inv);
      *(s16x4*)&orow[nc * 16 + g * 4] = P.v;
    }
  };
  epilogue(oA, lA, qbaseA);
  epilogue(oB, lB, qbaseB);
}

extern "C" void kernel_launch(void* const* d_in, const int* in_sizes, int n_in,
                              void* d_out, int out_size, void* d_ws, size_t ws_size,
                              hipStream_t stream) {
  const float* queries = (const float*)d_in[0];
  const float* keys    = (const float*)d_in[1];
  const float* values  = (const float*)d_in[2];
  // d_in[3] = attn_mask: exact causal triu(k=1), applied analytically.
  const float* Wq = (const float*)d_in[4];
  const float* bq = (const float*)d_in[5];
  const float* Wk = (const float*)d_in[6];
  const float* bk = (const float*)d_in[7];
  const float* Wv = (const float*)d_in[8];
  const float* bv = (const float*)d_in[9];
  const float* Wo = (const float*)d_in[10];
  const float* bo = (const float*)d_in[11];

  const size_t MD = (size_t)8192 * 1024;   // activation elems
  const size_t WN = (size_t)1024 * 1024;   // weight elems
  u16* qbuf = (u16*)d_ws;
  u16* kbuf = qbuf + MD;
  u16* vbuf = kbuf + MD;
  u16* abuf = vbuf + MD;

  dim3 blk(256);
  dim3 ggrid(8, 64);

  const size_t need = (4 * MD + 4 * WN) * sizeof(u16);
  if (ws_size >= need) {
    u16* qcv = abuf;
    u16* kcv = qbuf;
    u16* vcv = kbuf;
    u16* wqb = abuf + MD;
    u16* wkb = wqb + WN;
    u16* wvb = wkb + WN;
    u16* wob = wvb + WN;

    cvtbf<<<dim3(4096), blk, 0, stream>>>(queries, qcv, (int)(MD / 8));
    cvtbf<<<dim3(4096), blk, 0, stream>>>(keys,    kcv, (int)(MD / 8));
    cvtbf<<<dim3(4096), blk, 0, stream>>>(values,  vcv, (int)(MD / 8));
    cvtbf<<<dim3(512),  blk, 0, stream>>>(Wq, wqb, (int)(WN / 8));
    cvtbf<<<dim3(512),  blk, 0, stream>>>(Wk, wkb, (int)(WN / 8));
    cvtbf<<<dim3(512),  blk, 0, stream>>>(Wv, wvb, (int)(WN / 8));
    cvtbf<<<dim3(512),  blk, 0, stream>>>(Wo, wob, (int)(WN / 8));

    gemm_lds<2><<<ggrid, blk, 0, stream>>>(vcv, wvb, bv, vbuf, 8192, 1024, 1024);
    gemm_lds<1><<<ggrid, blk, 0, stream>>>(kcv, wkb, bk, kbuf, 8192, 1024, 1024);
    gemm_lds<1><<<ggrid, blk, 0, stream>>>(qcv, wqb, bq, qbuf, 8192, 1024, 1024);
    attn_kernel<<<dim3(1024), blk, 0, stream>>>(qbuf, kbuf, vbuf, abuf);
    gemm_lds<0><<<ggrid, blk, 0, stream>>>(abuf, wob, bo, d_out, 8192, 1024, 1024);
  } else {
    gemm_bt<0, 1><<<ggrid, blk, 0, stream>>>(queries, Wq, bq, qbuf, 8192, 1024, 1024);
    gemm_bt<0, 1><<<ggrid, blk, 0, stream>>>(keys,    Wk, bk, kbuf, 8192, 1024, 1024);
    gemm_bt<0, 2><<<ggrid, blk, 0, stream>>>(values,  Wv, bv, vbuf, 8192, 1024, 1024);
    attn_kernel<<<dim3(1024), blk, 0, stream>>>(qbuf, kbuf, vbuf, abuf);
    gemm_bt<1, 0><<<ggrid, blk, 0, stream>>>(abuf, Wo, bo, d_out, 8192, 1024, 1024);
  }
}

// Round 13
// 344.957 us; speedup vs baseline: 1.5140x; 1.0010x over previous
//
#include <hip/hip_runtime.h>
#include <hip/hip_bf16.h>

typedef float f32x4 __attribute__((ext_vector_type(4)));
typedef short s16x8 __attribute__((ext_vector_type(8)));
typedef short s16x4 __attribute__((ext_vector_type(4)));
typedef unsigned short u16;

#define H_ 16
#define E_ 64
#define D_ 1024
#define L_ 2048
#define NQT 32   // 64-row q tiles per (b,h)

__device__ __forceinline__ u16 f2bf(float f) {
  union { float f; unsigned u; } v; v.f = f;
  unsigned u = v.u;
  u += 0x7fffu + ((u >> 16) & 1u);   // round-to-nearest-even
  return (u16)(u >> 16);
}

// pack 2 f32 -> 2 bf16 in one u32 (lo=a, hi=b). NON-volatile: schedulable.
__device__ __forceinline__ unsigned pkbf(float a, float b) {
  unsigned r;
  asm("v_cvt_pk_bf16_f32 %0, %1, %2" : "=v"(r) : "v"(a), "v"(b));
  return r;
}

// async global->LDS, 16B per lane. lds base must be wave-uniform; HW adds lane*16.
__device__ __forceinline__ void gld16(const u16* g, u16* l) {
  __builtin_amdgcn_global_load_lds((const __attribute__((address_space(1))) void*)g,
                                   (__attribute__((address_space(3))) void*)l, 16, 0, 0);
}

// f32 -> bf16 bulk convert, 8 elems/thread
__global__ __launch_bounds__(256) void cvtbf(const float* __restrict__ in,
                                             u16* __restrict__ out, int n8) {
  const int i = blockIdx.x * 256 + threadIdx.x;
  if (i < n8) {
    const f32x4 a = *(const f32x4*)(in + (size_t)i * 8);
    const f32x4 b = *(const f32x4*)(in + (size_t)i * 8 + 4);
    s16x8 r;
#pragma unroll
    for (int j = 0; j < 4; ++j) { r[j] = (short)f2bf(a[j]); r[j + 4] = (short)f2bf(b[j]); }
    *(s16x8*)(out + (size_t)i * 8) = r;
  }
}

// ---------- bf16 GEMM, m97 recipe: global_load_lds staging, 2 barriers/iter ----
template<int PERMUTE>
__global__ __launch_bounds__(256) void gemm_lds(const u16* __restrict__ A,
                                                const u16* __restrict__ W,
                                                const float* __restrict__ bias,
                                                void* __restrict__ outp,
                                                int M, int N, int K)
{
  __shared__ __align__(16) u16 As[128][32];   // 64B rows: 2-way bank alias (free)
  __shared__ __align__(16) u16 Bs[128][32];
  const int tid = threadIdx.x;
  const int m0 = blockIdx.y * 128, n0 = blockIdx.x * 128;
  const int w = tid >> 6, lane = tid & 63, g = lane >> 4, li = lane & 15;
  const int wr = w >> 1, wc = w & 1;
  const int r0 = lane >> 2, cc = (lane & 3) * 8;

  f32x4 acc[4][4];
#pragma unroll
  for (int i = 0; i < 4; ++i)
#pragma unroll
    for (int j = 0; j < 4; ++j) acc[i][j] = (f32x4){0.f, 0.f, 0.f, 0.f};

  for (int k0 = 0; k0 < K; k0 += 32) {
#pragma unroll
    for (int i = 0; i < 2; ++i) {
      const int ch = w * 2 + i;
      const int row = ch * 16 + r0;
      gld16(A + (size_t)(m0 + row) * K + k0 + cc, &As[ch * 16][0]);
      gld16(W + (size_t)(n0 + row) * K + k0 + cc, &Bs[ch * 16][0]);
    }
    __syncthreads();

    s16x8 a[4], b[4];
#pragma unroll
    for (int mi = 0; mi < 4; ++mi) a[mi] = *(const s16x8*)&As[wr * 64 + mi * 16 + li][g * 8];
#pragma unroll
    for (int ni = 0; ni < 4; ++ni) b[ni] = *(const s16x8*)&Bs[wc * 64 + ni * 16 + li][g * 8];
#pragma unroll
    for (int mi = 0; mi < 4; ++mi)
#pragma unroll
      for (int ni = 0; ni < 4; ++ni)
        acc[mi][ni] = __builtin_amdgcn_mfma_f32_16x16x32_bf16(a[mi], b[ni], acc[mi][ni], 0, 0, 0);
    __syncthreads();
  }

#pragma unroll
  for (int mi = 0; mi < 4; ++mi) {
#pragma unroll
    for (int ni = 0; ni < 4; ++ni) {
      const int row = m0 + wr * 64 + mi * 16 + g * 4;
      const int col = n0 + wc * 64 + ni * 16 + li;
      const float bv = bias[col];
      if (PERMUTE == 2) {
        s16x4 pk;
#pragma unroll
        for (int r = 0; r < 4; ++r) pk[r] = (short)f2bf(acc[mi][ni][r] + bv);
        const int bb = row >> 11, lq = row & (L_ - 1);
        const int hh = col >> 6, e = col & (E_ - 1);
        *(s16x4*)&((u16*)outp)[(((size_t)bb * H_ + hh) * E_ + e) * L_ + lq] = pk;
      } else {
#pragma unroll
        for (int r = 0; r < 4; ++r) {
          const float v = acc[mi][ni][r] + bv;
          const int rr = row + r;
          if (PERMUTE == 1) {
            const int bb = rr >> 11, lq = rr & (L_ - 1);
            const int hh = col >> 6, e = col & (E_ - 1);
            ((u16*)outp)[(((size_t)bb * H_ + hh) * L_ + lq) * E_ + e] = f2bf(v);
          } else {
            ((float*)outp)[(size_t)rr * N + col] = v;
          }
        }
      }
    }
  }
}

// ---------- fallback GEMM (reg-staged, f32 A converted on the fly) ------------
template<int A_BF16, int PERMUTE>
__global__ __launch_bounds__(256) void gemm_bt(const void* __restrict__ Aptr,
                                               const float* __restrict__ W,
                                               const float* __restrict__ bias,
                                               void* __restrict__ outp,
                                               int M, int N, int K)
{
  __shared__ __align__(16) short As[2][128][40];
  __shared__ __align__(16) short Bs[2][128][40];
  const int tid = threadIdx.x;
  const int m0 = blockIdx.y * 128, n0 = blockIdx.x * 128;
  const int w = tid >> 6, lane = tid & 63, g = lane >> 4, li = lane & 15;
  const int wr = w >> 1, wc = w & 1;

  f32x4 acc[4][4];
#pragma unroll
  for (int i = 0; i < 4; ++i)
#pragma unroll
    for (int j = 0; j < 4; ++j) acc[i][j] = (f32x4){0.f, 0.f, 0.f, 0.f};

  f32x4 ra0[2], ra1[2];
  s16x8 rab[2];
  f32x4 rb0[2], rb1[2];

  auto LOAD = [&](int k0) {
#pragma unroll
    for (int p = 0; p < 2; ++p) {
      const int c = p * 256 + tid, row = c >> 2, kc = (c & 3) * 8;
      if (A_BF16) {
        rab[p] = *(const s16x8*)((const u16*)Aptr + (size_t)(m0 + row) * K + k0 + kc);
      } else {
        const float* ap = (const float*)Aptr + (size_t)(m0 + row) * K + k0 + kc;
        ra0[p] = *(const f32x4*)ap; ra1[p] = *(const f32x4*)(ap + 4);
      }
      const float* wp = W + (size_t)(n0 + row) * K + k0 + kc;
      rb0[p] = *(const f32x4*)wp; rb1[p] = *(const f32x4*)(wp + 4);
    }
  };
  auto WRITE = [&](int buf) {
#pragma unroll
    for (int p = 0; p < 2; ++p) {
      const int c = p * 256 + tid, row = c >> 2, kc = (c & 3) * 8;
      if (A_BF16) {
        *(s16x8*)&As[buf][row][kc] = rab[p];
      } else {
        s16x8 r;
#pragma unroll
        for (int j = 0; j < 4; ++j) { r[j] = (short)f2bf(ra0[p][j]); r[j + 4] = (short)f2bf(ra1[p][j]); }
        *(s16x8*)&As[buf][row][kc] = r;
      }
      s16x8 rb;
#pragma unroll
      for (int j = 0; j < 4; ++j) { rb[j] = (short)f2bf(rb0[p][j]); rb[j + 4] = (short)f2bf(rb1[p][j]); }
      *(s16x8*)&Bs[buf][row][kc] = rb;
    }
  };

  LOAD(0); WRITE(0);
  __syncthreads();
  int cur = 0;
  for (int k0 = 0; k0 < K; k0 += 32) {
    const bool more = (k0 + 32 < K);
    if (more) LOAD(k0 + 32);

    s16x8 a[4], b[4];
#pragma unroll
    for (int mi = 0; mi < 4; ++mi) a[mi] = *(const s16x8*)&As[cur][wr * 64 + mi * 16 + li][g * 8];
#pragma unroll
    for (int ni = 0; ni < 4; ++ni) b[ni] = *(const s16x8*)&Bs[cur][wc * 64 + ni * 16 + li][g * 8];
#pragma unroll
    for (int mi = 0; mi < 4; ++mi)
#pragma unroll
      for (int ni = 0; ni < 4; ++ni)
        acc[mi][ni] = __builtin_amdgcn_mfma_f32_16x16x32_bf16(a[mi], b[ni], acc[mi][ni], 0, 0, 0);

    if (more) { WRITE(cur ^ 1); __syncthreads(); }
    cur ^= 1;
  }

#pragma unroll
  for (int mi = 0; mi < 4; ++mi) {
#pragma unroll
    for (int ni = 0; ni < 4; ++ni) {
      const int row = m0 + wr * 64 + mi * 16 + g * 4;
      const int col = n0 + wc * 64 + ni * 16 + li;
      const float bv = bias[col];
      if (PERMUTE == 2) {
        s16x4 pk;
#pragma unroll
        for (int r = 0; r < 4; ++r) pk[r] = (short)f2bf(acc[mi][ni][r] + bv);
        const int bb = row >> 11, lq = row & (L_ - 1);
        const int hh = col >> 6, e = col & (E_ - 1);
        *(s16x4*)&((u16*)outp)[(((size_t)bb * H_ + hh) * E_ + e) * L_ + lq] = pk;
      } else {
#pragma unroll
        for (int r = 0; r < 4; ++r) {
          const float v = acc[mi][ni][r] + bv;
          const int rr = row + r;
          if (PERMUTE == 1) {
            const int bb = rr >> 11, lq = rr & (L_ - 1);
            const int hh = col >> 6, e = col & (E_ - 1);
            ((u16*)outp)[(((size_t)bb * H_ + hh) * L_ + lq) * E_ + e] = f2bf(v);
          } else {
            ((float*)outp)[(size_t)rr * N + col] = v;
          }
        }
      }
    }
  }
}

// Flash attention, causal. Grid: 1024 (1D). Block: 256 (4 waves x 16 q rows).
// XCD-grouped; ALL-REGISTER; T15 double-pipeline: QK(t+1) is computed BETWEEN
// softmax(t) and PV(t), writing the p registers softmax just freed. softmax(t+1)
// therefore has a full iteration of slack behind its QK. Single kf/v buffers
// (loaded and consumed within one iteration).
__global__ __launch_bounds__(256) void attn_kernel(const u16* __restrict__ qp,
                                                   const u16* __restrict__ kp,
                                                   const u16* __restrict__ vtp,
                                                   u16* __restrict__ op)
{
  const int tid = threadIdx.x;
  const unsigned wgid = blockIdx.x;
  const int bh = (wgid & 7) * 8 + ((wgid >> 3) & 7);   // XCD c owns bh in [8c,8c+8)
  const int qx = wgid >> 6;
  const int w = tid >> 6, lane = tid & 63, g = lane >> 4, li = lane & 15;
  const float scl2e = 0.125f * 1.44269504089f;
  const size_t base  = (size_t)bh * L_ * E_;
  const size_t baseT = (size_t)bh * E_ * L_;
  const int bb = bh >> 4, hh = bh & 15;

  const int qbA = NQT - 1 - qx;
  const int qbB = qx;
  const int qbaseA = qbA * 64, qbaseB = qbB * 64;

  const u16* qrA = qp + base + (size_t)(qbaseA + w * 16 + li) * E_;
  const s16x8 qa0A = *(const s16x8*)(qrA + g * 8);
  const s16x8 qa1A = *(const s16x8*)(qrA + 32 + g * 8);
  const u16* qrB = qp + base + (size_t)(qbaseB + w * 16 + li) * E_;
  const s16x8 qa0B = *(const s16x8*)(qrB + g * 8);
  const s16x8 qa1B = *(const s16x8*)(qrB + 32 + g * 8);

  f32x4 oA[4], oB[4];
  float mA = -1e30f, lA = 0.f, mB = -1e30f, lB = 0.f;
#pragma unroll
  for (int nc = 0; nc < 4; ++nc) { oA[nc] = (f32x4){0.f,0.f,0.f,0.f}; oB[nc] = (f32x4){0.f,0.f,0.f,0.f}; }

  s16x8 kf[8];          // single buffer: loaded + consumed within one iteration
  s16x8 v0[4], v1[4];
  f32x4 pA[4], pB[4];   // pre-exp scores (log2 domain), one tile ahead

  const int kro = 8 * (li >> 2) + (li & 3);
  auto loadk = [&](int t) {
    const int kvb = t * 64;
#pragma unroll
    for (int inst = 0; inst < 4; ++inst) {
      const u16* kr = kp + base + (size_t)(kvb + 32 * (inst >> 1) + 4 * (inst & 1) + kro) * E_;
      kf[inst * 2]     = *(const s16x8*)(kr + g * 8);
      kf[inst * 2 + 1] = *(const s16x8*)(kr + 32 + g * 8);
    }
  };
  auto loadv = [&](int t) {
    const int kvb = t * 64;
#pragma unroll
    for (int nc = 0; nc < 4; ++nc) {
      const u16* vrow = vtp + baseT + (size_t)(nc * 16 + li) * L_ + kvb;
      v0[nc] = *(const s16x8*)(vrow + g * 8);
      v1[nc] = *(const s16x8*)(vrow + 32 + g * 8);
    }
  };
  // QK for tile t into p (scaled, masked if diagonal)
  auto qk = [&](const s16x8& q0, const s16x8& q1, f32x4* p, int t, int qb, int qbase) {
#pragma unroll
    for (int inst = 0; inst < 4; ++inst) {
      f32x4 sf = (f32x4){0.f, 0.f, 0.f, 0.f};
      sf = __builtin_amdgcn_mfma_f32_16x16x32_bf16(kf[inst * 2],     q0, sf, 0, 0, 0);
      sf = __builtin_amdgcn_mfma_f32_16x16x32_bf16(kf[inst * 2 + 1], q1, sf, 0, 0, 0);
#pragma unroll
      for (int r = 0; r < 4; ++r) p[inst][r] = sf[r] * scl2e;
    }
    if (t == qb) {
      const int qrow = qbase + w * 16 + li;
      const int kvb = t * 64;
#pragma unroll
      for (int inst = 0; inst < 4; ++inst)
#pragma unroll
        for (int r = 0; r < 4; ++r)
          if (kvb + 32 * (inst >> 1) + 8 * g + 4 * (inst & 1) + r > qrow) p[inst][r] = -1e30f;
    }
  };
  // softmax: consumes p, produces pk[8] + partial row-sum (reduced later)
  auto sm = [&](f32x4* p, float& m_run, float& l_run, f32x4* o, unsigned* pk) -> float {
    float m0_ = fmaxf(fmaxf(p[0][0], p[0][1]), fmaxf(p[0][2], p[0][3]));
    float m1_ = fmaxf(fmaxf(p[1][0], p[1][1]), fmaxf(p[1][2], p[1][3]));
    float m2_ = fmaxf(fmaxf(p[2][0], p[2][1]), fmaxf(p[2][2], p[2][3]));
    float m3_ = fmaxf(fmaxf(p[3][0], p[3][1]), fmaxf(p[3][2], p[3][3]));
    float mx = fmaxf(fmaxf(m0_, m1_), fmaxf(m2_, m3_));
    mx = fmaxf(mx, __shfl_xor(mx, 16));
    mx = fmaxf(mx, __shfl_xor(mx, 32));
    const bool resc = __any(mx > m_run + 8.0f);   // defer-max (log2 domain)
    if (resc) {
      const float mn = fmaxf(m_run, mx);
      const float alpha = __builtin_amdgcn_exp2f(m_run - mn);
      m_run = mn;
      l_run *= alpha;
#pragma unroll
      for (int nc = 0; nc < 4; ++nc)
#pragma unroll
        for (int r = 0; r < 4; ++r) o[nc][r] *= alpha;
    }
    float rs = 0.f;
#pragma unroll
    for (int inst = 0; inst < 4; ++inst) {
      const float e0 = __builtin_amdgcn_exp2f(p[inst][0] - m_run);
      const float e1 = __builtin_amdgcn_exp2f(p[inst][1] - m_run);
      const float e2 = __builtin_amdgcn_exp2f(p[inst][2] - m_run);
      const float e3 = __builtin_amdgcn_exp2f(p[inst][3] - m_run);
      rs += (e0 + e1) + (e2 + e3);
      pk[inst * 2]     = pkbf(e0, e1);
      pk[inst * 2 + 1] = pkbf(e2, e3);
    }
    return rs;
  };
  auto pv = [&](const unsigned* pk, f32x4* o) {
    union { s16x8 v; unsigned u[4]; } A0, A1;
    A0.u[0] = pk[0]; A0.u[1] = pk[1]; A0.u[2] = pk[2]; A0.u[3] = pk[3];
    A1.u[0] = pk[4]; A1.u[1] = pk[5]; A1.u[2] = pk[6]; A1.u[3] = pk[7];
#pragma unroll
    for (int nc = 0; nc < 4; ++nc) {
      o[nc] = __builtin_amdgcn_mfma_f32_16x16x32_bf16(v0[nc], A0.v, o[nc], 0, 0, 0);
      o[nc] = __builtin_amdgcn_mfma_f32_16x16x32_bf16(v1[nc], A1.v, o[nc], 0, 0, 0);
    }
  };

  // prologue: K(0) + QK(0) for both chains
  loadk(0);
  qk(qa0A, qa1A, pA, 0, qbA, qbaseA);
  qk(qa0B, qa1B, pB, 0, qbB, qbaseB);

  unsigned pkA[8], pkB[8];
  for (int t = 0; t <= qbA; ++t) {
    loadv(t);                                  // V(t): oldest vmcnt slots
    const bool more  = (t + 1 <= qbA);
    const bool doB   = (t     <= qbB);
    const bool moreB = (t + 1 <= qbB);
    if (more) loadk(t + 1);                    // K(t+1): in flight during softmax

    float rsA = sm(pA, mA, lA, oA, pkA);       // consumes pA -> pA free
    float rsB = 0.f;
    if (doB) rsB = sm(pB, mB, lB, oB, pkB);

    if (more)  qk(qa0A, qa1A, pA, t + 1, qbA, qbaseA);   // QK(t+1) fills stall
    if (moreB) qk(qa0B, qa1B, pB, t + 1, qbB, qbaseB);

    pv(pkA, oA);                               // v arrived (older than kf)
    if (doB) pv(pkB, oB);

    rsA += __shfl_xor(rsA, 16); rsA += __shfl_xor(rsA, 32);
    lA += rsA;
    if (doB) { rsB += __shfl_xor(rsB, 16); rsB += __shfl_xor(rsB, 32); lB += rsB; }
  }

  auto epilogue = [&](const f32x4* o, float l_run, int qbase) {
    const float inv = 1.0f / l_run;
    u16* orow = op + ((size_t)bb * L_ + qbase + w * 16 + li) * D_ + hh * E_;
#pragma unroll
    for (int nc = 0; nc < 4; ++nc) {
      union { s16x4 v; unsigned u[2]; } P;
      P.u[0] = pkbf(o[nc][0] * inv, o[nc][1] * inv);
      P.u[1] = pkbf(o[nc][2] * inv, o[nc][3] * inv);
      *(s16x4*)&orow[nc * 16 + g * 4] = P.v;
    }
  };
  epilogue(oA, lA, qbaseA);
  epilogue(oB, lB, qbaseB);
}

extern "C" void kernel_launch(void* const* d_in, const int* in_sizes, int n_in,
                              void* d_out, int out_size, void* d_ws, size_t ws_size,
                              hipStream_t stream) {
  const float* queries = (const float*)d_in[0];
  const float* keys    = (const float*)d_in[1];
  const float* values  = (const float*)d_in[2];
  // d_in[3] = attn_mask: exact causal triu(k=1), applied analytically.
  const float* Wq = (const float*)d_in[4];
  const float* bq = (const float*)d_in[5];
  const float* Wk = (const float*)d_in[6];
  const float* bk = (const float*)d_in[7];
  const float* Wv = (const float*)d_in[8];
  const float* bv = (const float*)d_in[9];
  const float* Wo = (const float*)d_in[10];
  const float* bo = (const float*)d_in[11];

  const size_t MD = (size_t)8192 * 1024;   // activation elems
  const size_t WN = (size_t)1024 * 1024;   // weight elems
  u16* qbuf = (u16*)d_ws;
  u16* kbuf = qbuf + MD;
  u16* vbuf = kbuf + MD;
  u16* abuf = vbuf + MD;

  dim3 blk(256);
  dim3 ggrid(8, 64);

  const size_t need = (4 * MD + 4 * WN) * sizeof(u16);
  if (ws_size >= need) {
    u16* qcv = abuf;
    u16* kcv = qbuf;
    u16* vcv = kbuf;
    u16* wqb = abuf + MD;
    u16* wkb = wqb + WN;
    u16* wvb = wkb + WN;
    u16* wob = wvb + WN;

    cvtbf<<<dim3(4096), blk, 0, stream>>>(queries, qcv, (int)(MD / 8));
    cvtbf<<<dim3(4096), blk, 0, stream>>>(keys,    kcv, (int)(MD / 8));
    cvtbf<<<dim3(4096), blk, 0, stream>>>(values,  vcv, (int)(MD / 8));
    cvtbf<<<dim3(512),  blk, 0, stream>>>(Wq, wqb, (int)(WN / 8));
    cvtbf<<<dim3(512),  blk, 0, stream>>>(Wk, wkb, (int)(WN / 8));
    cvtbf<<<dim3(512),  blk, 0, stream>>>(Wv, wvb, (int)(WN / 8));
    cvtbf<<<dim3(512),  blk, 0, stream>>>(Wo, wob, (int)(WN / 8));

    gemm_lds<2><<<ggrid, blk, 0, stream>>>(vcv, wvb, bv, vbuf, 8192, 1024, 1024);
    gemm_lds<1><<<ggrid, blk, 0, stream>>>(kcv, wkb, bk, kbuf, 8192, 1024, 1024);
    gemm_lds<1><<<ggrid, blk, 0, stream>>>(qcv, wqb, bq, qbuf, 8192, 1024, 1024);
    attn_kernel<<<dim3(1024), blk, 0, stream>>>(qbuf, kbuf, vbuf, abuf);
    gemm_lds<0><<<ggrid, blk, 0, stream>>>(abuf, wob, bo, d_out, 8192, 1024, 1024);
  } else {
    gemm_bt<0, 1><<<ggrid, blk, 0, stream>>>(queries, Wq, bq, qbuf, 8192, 1024, 1024);
    gemm_bt<0, 1><<<ggrid, blk, 0, stream>>>(keys,    Wk, bk, kbuf, 8192, 1024, 1024);
    gemm_bt<0, 2><<<ggrid, blk, 0, stream>>>(values,  Wv, bv, vbuf, 8192, 1024, 1024);
    attn_kernel<<<dim3(1024), blk, 0, stream>>>(qbuf, kbuf, vbuf, abuf);
    gemm_bt<1, 0><<<ggrid, blk, 0, stream>>>(abuf, Wo, bo, d_out, 8192, 1024, 1024);
  }
}

// Round 14
// 245.470 us; speedup vs baseline: 2.1276x; 1.4053x over previous
//
#include <hip/hip_runtime.h>
#include <hip/hip_bf16.h>

typedef float f32x4 __attribute__((ext_vector_type(4)));
typedef short s16x8 __attribute__((ext_vector_type(8)));
typedef short s16x4 __attribute__((ext_vector_type(4)));
typedef unsigned short u16;

#define H_ 16
#define E_ 64
#define D_ 1024
#define L_ 2048
#define NQT 32   // 64-row q tiles per (b,h)

__device__ __forceinline__ u16 f2bf(float f) {
  union { float f; unsigned u; } v; v.f = f;
  unsigned u = v.u;
  u += 0x7fffu + ((u >> 16) & 1u);   // round-to-nearest-even
  return (u16)(u >> 16);
}

// pack 2 f32 -> 2 bf16 in one u32 (lo=a, hi=b). NON-volatile: schedulable.
__device__ __forceinline__ unsigned pkbf(float a, float b) {
  unsigned r;
  asm("v_cvt_pk_bf16_f32 %0, %1, %2" : "=v"(r) : "v"(a), "v"(b));
  return r;
}

// async global->LDS, 16B per lane. lds base must be wave-uniform; HW adds lane*16.
__device__ __forceinline__ void gld16(const u16* g, u16* l) {
  __builtin_amdgcn_global_load_lds((const __attribute__((address_space(1))) void*)g,
                                   (__attribute__((address_space(3))) void*)l, 16, 0, 0);
}

// f32 -> bf16 bulk convert, 8 elems/thread
__global__ __launch_bounds__(256) void cvtbf(const float* __restrict__ in,
                                             u16* __restrict__ out, int n8) {
  const int i = blockIdx.x * 256 + threadIdx.x;
  if (i < n8) {
    const f32x4 a = *(const f32x4*)(in + (size_t)i * 8);
    const f32x4 b = *(const f32x4*)(in + (size_t)i * 8 + 4);
    s16x8 r;
#pragma unroll
    for (int j = 0; j < 4; ++j) { r[j] = (short)f2bf(a[j]); r[j + 4] = (short)f2bf(b[j]); }
    *(s16x8*)(out + (size_t)i * 8) = r;
  }
}

// ---------- bf16 GEMM, m97 recipe: global_load_lds staging, 2 barriers/iter ----
template<int PERMUTE>
__global__ __launch_bounds__(256) void gemm_lds(const u16* __restrict__ A,
                                                const u16* __restrict__ W,
                                                const float* __restrict__ bias,
                                                void* __restrict__ outp,
                                                int M, int N, int K)
{
  __shared__ __align__(16) u16 As[128][32];
  __shared__ __align__(16) u16 Bs[128][32];
  const int tid = threadIdx.x;
  const int m0 = blockIdx.y * 128, n0 = blockIdx.x * 128;
  const int w = tid >> 6, lane = tid & 63, g = lane >> 4, li = lane & 15;
  const int wr = w >> 1, wc = w & 1;
  const int r0 = lane >> 2, cc = (lane & 3) * 8;

  f32x4 acc[4][4];
#pragma unroll
  for (int i = 0; i < 4; ++i)
#pragma unroll
    for (int j = 0; j < 4; ++j) acc[i][j] = (f32x4){0.f, 0.f, 0.f, 0.f};

  for (int k0 = 0; k0 < K; k0 += 32) {
#pragma unroll
    for (int i = 0; i < 2; ++i) {
      const int ch = w * 2 + i;
      const int row = ch * 16 + r0;
      gld16(A + (size_t)(m0 + row) * K + k0 + cc, &As[ch * 16][0]);
      gld16(W + (size_t)(n0 + row) * K + k0 + cc, &Bs[ch * 16][0]);
    }
    __syncthreads();

    s16x8 a[4], b[4];
#pragma unroll
    for (int mi = 0; mi < 4; ++mi) a[mi] = *(const s16x8*)&As[wr * 64 + mi * 16 + li][g * 8];
#pragma unroll
    for (int ni = 0; ni < 4; ++ni) b[ni] = *(const s16x8*)&Bs[wc * 64 + ni * 16 + li][g * 8];
#pragma unroll
    for (int mi = 0; mi < 4; ++mi)
#pragma unroll
      for (int ni = 0; ni < 4; ++ni)
        acc[mi][ni] = __builtin_amdgcn_mfma_f32_16x16x32_bf16(a[mi], b[ni], acc[mi][ni], 0, 0, 0);
    __syncthreads();
  }

#pragma unroll
  for (int mi = 0; mi < 4; ++mi) {
#pragma unroll
    for (int ni = 0; ni < 4; ++ni) {
      const int row = m0 + wr * 64 + mi * 16 + g * 4;
      const int col = n0 + wc * 64 + ni * 16 + li;
      const float bv = bias[col];
      if (PERMUTE == 2) {
        s16x4 pk;
#pragma unroll
        for (int r = 0; r < 4; ++r) pk[r] = (short)f2bf(acc[mi][ni][r] + bv);
        const int bb = row >> 11, lq = row & (L_ - 1);
        const int hh = col >> 6, e = col & (E_ - 1);
        *(s16x4*)&((u16*)outp)[(((size_t)bb * H_ + hh) * E_ + e) * L_ + lq] = pk;
      } else {
#pragma unroll
        for (int r = 0; r < 4; ++r) {
          const float v = acc[mi][ni][r] + bv;
          const int rr = row + r;
          if (PERMUTE == 1) {
            const int bb = rr >> 11, lq = rr & (L_ - 1);
            const int hh = col >> 6, e = col & (E_ - 1);
            ((u16*)outp)[(((size_t)bb * H_ + hh) * L_ + lq) * E_ + e] = f2bf(v);
          } else {
            ((float*)outp)[(size_t)rr * N + col] = v;
          }
        }
      }
    }
  }
}

// ---------- fallback GEMM (reg-staged, f32 A converted on the fly) ------------
template<int A_BF16, int PERMUTE>
__global__ __launch_bounds__(256) void gemm_bt(const void* __restrict__ Aptr,
                                               const float* __restrict__ W,
                                               const float* __restrict__ bias,
                                               void* __restrict__ outp,
                                               int M, int N, int K)
{
  __shared__ __align__(16) short As[2][128][40];
  __shared__ __align__(16) short Bs[2][128][40];
  const int tid = threadIdx.x;
  const int m0 = blockIdx.y * 128, n0 = blockIdx.x * 128;
  const int w = tid >> 6, lane = tid & 63, g = lane >> 4, li = lane & 15;
  const int wr = w >> 1, wc = w & 1;

  f32x4 acc[4][4];
#pragma unroll
  for (int i = 0; i < 4; ++i)
#pragma unroll
    for (int j = 0; j < 4; ++j) acc[i][j] = (f32x4){0.f, 0.f, 0.f, 0.f};

  f32x4 ra0[2], ra1[2];
  s16x8 rab[2];
  f32x4 rb0[2], rb1[2];

  auto LOAD = [&](int k0) {
#pragma unroll
    for (int p = 0; p < 2; ++p) {
      const int c = p * 256 + tid, row = c >> 2, kc = (c & 3) * 8;
      if (A_BF16) {
        rab[p] = *(const s16x8*)((const u16*)Aptr + (size_t)(m0 + row) * K + k0 + kc);
      } else {
        const float* ap = (const float*)Aptr + (size_t)(m0 + row) * K + k0 + kc;
        ra0[p] = *(const f32x4*)ap; ra1[p] = *(const f32x4*)(ap + 4);
      }
      const float* wp = W + (size_t)(n0 + row) * K + k0 + kc;
      rb0[p] = *(const f32x4*)wp; rb1[p] = *(const f32x4*)(wp + 4);
    }
  };
  auto WRITE = [&](int buf) {
#pragma unroll
    for (int p = 0; p < 2; ++p) {
      const int c = p * 256 + tid, row = c >> 2, kc = (c & 3) * 8;
      if (A_BF16) {
        *(s16x8*)&As[buf][row][kc] = rab[p];
      } else {
        s16x8 r;
#pragma unroll
        for (int j = 0; j < 4; ++j) { r[j] = (short)f2bf(ra0[p][j]); r[j + 4] = (short)f2bf(ra1[p][j]); }
        *(s16x8*)&As[buf][row][kc] = r;
      }
      s16x8 rb;
#pragma unroll
      for (int j = 0; j < 4; ++j) { rb[j] = (short)f2bf(rb0[p][j]); rb[j + 4] = (short)f2bf(rb1[p][j]); }
      *(s16x8*)&Bs[buf][row][kc] = rb;
    }
  };

  LOAD(0); WRITE(0);
  __syncthreads();
  int cur = 0;
  for (int k0 = 0; k0 < K; k0 += 32) {
    const bool more = (k0 + 32 < K);
    if (more) LOAD(k0 + 32);

    s16x8 a[4], b[4];
#pragma unroll
    for (int mi = 0; mi < 4; ++mi) a[mi] = *(const s16x8*)&As[cur][wr * 64 + mi * 16 + li][g * 8];
#pragma unroll
    for (int ni = 0; ni < 4; ++ni) b[ni] = *(const s16x8*)&Bs[cur][wc * 64 + ni * 16 + li][g * 8];
#pragma unroll
    for (int mi = 0; mi < 4; ++mi)
#pragma unroll
      for (int ni = 0; ni < 4; ++ni)
        acc[mi][ni] = __builtin_amdgcn_mfma_f32_16x16x32_bf16(a[mi], b[ni], acc[mi][ni], 0, 0, 0);

    if (more) { WRITE(cur ^ 1); __syncthreads(); }
    cur ^= 1;
  }

#pragma unroll
  for (int mi = 0; mi < 4; ++mi) {
#pragma unroll
    for (int ni = 0; ni < 4; ++ni) {
      const int row = m0 + wr * 64 + mi * 16 + g * 4;
      const int col = n0 + wc * 64 + ni * 16 + li;
      const float bv = bias[col];
      if (PERMUTE == 2) {
        s16x4 pk;
#pragma unroll
        for (int r = 0; r < 4; ++r) pk[r] = (short)f2bf(acc[mi][ni][r] + bv);
        const int bb = row >> 11, lq = row & (L_ - 1);
        const int hh = col >> 6, e = col & (E_ - 1);
        *(s16x4*)&((u16*)outp)[(((size_t)bb * H_ + hh) * E_ + e) * L_ + lq] = pk;
      } else {
#pragma unroll
        for (int r = 0; r < 4; ++r) {
          const float v = acc[mi][ni][r] + bv;
          const int rr = row + r;
          if (PERMUTE == 1) {
            const int bb = rr >> 11, lq = rr & (L_ - 1);
            const int hh = col >> 6, e = col & (E_ - 1);
            ((u16*)outp)[(((size_t)bb * H_ + hh) * L_ + lq) * E_ + e] = f2bf(v);
          } else {
            ((float*)outp)[(size_t)rr * N + col] = v;
          }
        }
      }
    }
  }
}

// Flash attention, causal. Grid: 1024 (1D). Block: 256 (4 waves x 16 q rows).
// XCD-grouped bh mapping. K/V tiles staged in LDS ONCE per block via
// global_load_lds (double-buffered, one __syncthreads per tile) -- cuts the
// per-CU vector-memory delivery 4x vs per-wave private loads (R13 bottleneck).
// LDS layout XOR-swizzled (slot s holds [row=s>>3][col8=(s&7)^swz(row)],
// swz(row)=(row&3)|(((row>>3)&1)<<2)) so fragment ds_read_b128 is 2-way max.
// Softmax/P pipeline stays all-register (swapped QK^T, defer-max, log2).
__global__ __launch_bounds__(256) void attn_kernel(const u16* __restrict__ qp,
                                                   const u16* __restrict__ kp,
                                                   const u16* __restrict__ vtp,
                                                   u16* __restrict__ op)
{
  __shared__ __align__(16) u16 Ks[2][4096];   // 8KB per buf
  __shared__ __align__(16) u16 Vs[2][4096];
  const int tid = threadIdx.x;
  const unsigned wgid = blockIdx.x;
  const int bh = (wgid & 7) * 8 + ((wgid >> 3) & 7);   // XCD c owns bh in [8c,8c+8)
  const int qx = wgid >> 6;
  const int w = tid >> 6, lane = tid & 63, g = lane >> 4, li = lane & 15;
  const float scl2e = 0.125f * 1.44269504089f;
  const size_t base  = (size_t)bh * L_ * E_;
  const size_t baseT = (size_t)bh * E_ * L_;
  const int bb = bh >> 4, hh = bh & 15;

  const int qbA = NQT - 1 - qx;
  const int qbB = qx;
  const int qbaseA = qbA * 64, qbaseB = qbB * 64;

  const u16* qrA = qp + base + (size_t)(qbaseA + w * 16 + li) * E_;
  const s16x8 qa0A = *(const s16x8*)(qrA + g * 8);
  const s16x8 qa1A = *(const s16x8*)(qrA + 32 + g * 8);
  const u16* qrB = qp + base + (size_t)(qbaseB + w * 16 + li) * E_;
  const s16x8 qa0B = *(const s16x8*)(qrB + g * 8);
  const s16x8 qa1B = *(const s16x8*)(qrB + 32 + g * 8);

  f32x4 oA[4], oB[4];
  float mA = -1e30f, lA = 0.f, mB = -1e30f, lB = 0.f;   // per-lane, q = w*16+li
#pragma unroll
  for (int nc = 0; nc < 4; ++nc) { oA[nc] = (f32x4){0.f,0.f,0.f,0.f}; oB[nc] = (f32x4){0.f,0.f,0.f,0.f}; }

  // staging source offsets (pre-swizzled global source, linear LDS dest)
  int kSrc[2], vSrc[2];
#pragma unroll
  for (int j = 0; j < 2; ++j) {
    const int s = (w * 2 + j) * 64 + lane;
    const int row = s >> 3;
    const int c8 = (s & 7) ^ ((row & 3) | (((row >> 3) & 1) << 2));
    kSrc[j] = row * E_ + c8 * 8;
    vSrc[j] = row * L_ + c8 * 8;   // row = e for V^T
  }
  auto stage = [&](int t, int buf) {
    const int kvb = t * 64;
#pragma unroll
    for (int j = 0; j < 2; ++j) {
      gld16(kp + base + (size_t)kvb * E_ + kSrc[j], &Ks[buf][(w * 2 + j) * 512]);
      gld16(vtp + baseT + kvb + vSrc[j],            &Vs[buf][(w * 2 + j) * 512]);
    }
  };

  // fragment read offsets (u16 index into 4096-elem buffer)
  const int swzk = li & 7;
  const int swzv = (li & 3) | (((li >> 3) & 1) << 2);
  int kRd[8], vRd[8];
#pragma unroll
  for (int inst = 0; inst < 4; ++inst) {
    const int bs = (32 * (inst >> 1) + 4 * (inst & 1) + 8 * (li >> 2) + (li & 3)) * 8;
    kRd[inst * 2]     = (bs + (g ^ swzk)) * 8;
    kRd[inst * 2 + 1] = (bs + ((g + 4) ^ swzk)) * 8;
  }
#pragma unroll
  for (int nc = 0; nc < 4; ++nc) {
    const int es = (nc * 16 + li) * 8;
    vRd[nc * 2]     = (es + (g ^ swzv)) * 8;
    vRd[nc * 2 + 1] = (es + ((g + 4) ^ swzv)) * 8;
  }

  auto qk = [&](const s16x8* kf, const s16x8& q0, const s16x8& q1, f32x4* p,
                int t, int qb, int qbase) {
#pragma unroll
    for (int inst = 0; inst < 4; ++inst) {
      f32x4 sf = (f32x4){0.f, 0.f, 0.f, 0.f};
      sf = __builtin_amdgcn_mfma_f32_16x16x32_bf16(kf[inst * 2],     q0, sf, 0, 0, 0);
      sf = __builtin_amdgcn_mfma_f32_16x16x32_bf16(kf[inst * 2 + 1], q1, sf, 0, 0, 0);
#pragma unroll
      for (int r = 0; r < 4; ++r) p[inst][r] = sf[r] * scl2e;
    }
    if (t == qb) {
      const int qrow = qbase + w * 16 + li;
      const int kvb = t * 64;
#pragma unroll
      for (int inst = 0; inst < 4; ++inst)
#pragma unroll
        for (int r = 0; r < 4; ++r)
          if (kvb + 32 * (inst >> 1) + 8 * g + 4 * (inst & 1) + r > qrow) p[inst][r] = -1e30f;
    }
  };
  auto sm = [&](f32x4* p, float& m_run, float& l_run, f32x4* o, unsigned* pk) -> float {
    float m0_ = fmaxf(fmaxf(p[0][0], p[0][1]), fmaxf(p[0][2], p[0][3]));
    float m1_ = fmaxf(fmaxf(p[1][0], p[1][1]), fmaxf(p[1][2], p[1][3]));
    float m2_ = fmaxf(fmaxf(p[2][0], p[2][1]), fmaxf(p[2][2], p[2][3]));
    float m3_ = fmaxf(fmaxf(p[3][0], p[3][1]), fmaxf(p[3][2], p[3][3]));
    float mx = fmaxf(fmaxf(m0_, m1_), fmaxf(m2_, m3_));
    mx = fmaxf(mx, __shfl_xor(mx, 16));
    mx = fmaxf(mx, __shfl_xor(mx, 32));
    const bool resc = __any(mx > m_run + 8.0f);
    if (resc) {
      const float mn = fmaxf(m_run, mx);
      const float alpha = __builtin_amdgcn_exp2f(m_run - mn);
      m_run = mn;
      l_run *= alpha;
#pragma unroll
      for (int nc = 0; nc < 4; ++nc)
#pragma unroll
        for (int r = 0; r < 4; ++r) o[nc][r] *= alpha;
    }
    float rs = 0.f;
#pragma unroll
    for (int inst = 0; inst < 4; ++inst) {
      const float e0 = __builtin_amdgcn_exp2f(p[inst][0] - m_run);
      const float e1 = __builtin_amdgcn_exp2f(p[inst][1] - m_run);
      const float e2 = __builtin_amdgcn_exp2f(p[inst][2] - m_run);
      const float e3 = __builtin_amdgcn_exp2f(p[inst][3] - m_run);
      rs += (e0 + e1) + (e2 + e3);
      pk[inst * 2]     = pkbf(e0, e1);
      pk[inst * 2 + 1] = pkbf(e2, e3);
    }
    return rs;
  };
  auto pv = [&](const s16x8* vf, const unsigned* pk, f32x4* o) {
    union { s16x8 v; unsigned u[4]; } A0, A1;
    A0.u[0] = pk[0]; A0.u[1] = pk[1]; A0.u[2] = pk[2]; A0.u[3] = pk[3];
    A1.u[0] = pk[4]; A1.u[1] = pk[5]; A1.u[2] = pk[6]; A1.u[3] = pk[7];
#pragma unroll
    for (int nc = 0; nc < 4; ++nc) {
      o[nc] = __builtin_amdgcn_mfma_f32_16x16x32_bf16(vf[nc * 2],     A0.v, o[nc], 0, 0, 0);
      o[nc] = __builtin_amdgcn_mfma_f32_16x16x32_bf16(vf[nc * 2 + 1], A1.v, o[nc], 0, 0, 0);
    }
  };

  stage(0, 0);
  __syncthreads();
  int buf = 0;
  unsigned pkA[8], pkB[8];
  for (int t = 0; t <= qbA; ++t) {
    const bool more = (t < qbA);
    const bool doB  = (t <= qbB);
    if (more) stage(t + 1, buf ^ 1);          // async into other buffer

    s16x8 kf[8];
#pragma unroll
    for (int i = 0; i < 8; ++i) kf[i] = *(const s16x8*)&Ks[buf][kRd[i]];
    f32x4 pA[4], pB[4];
    qk(kf, qa0A, qa1A, pA, t, qbA, qbaseA);
    if (doB) qk(kf, qa0B, qa1B, pB, t, qbB, qbaseB);

    s16x8 vf[8];                               // issued before sm: latency hidden
#pragma unroll
    for (int i = 0; i < 8; ++i) vf[i] = *(const s16x8*)&Vs[buf][vRd[i]];

    float rsA = sm(pA, mA, lA, oA, pkA);
    float rsB = 0.f;
    if (doB) rsB = sm(pB, mB, lB, oB, pkB);

    pv(vf, pkA, oA);
    if (doB) pv(vf, pkB, oB);

    rsA += __shfl_xor(rsA, 16); rsA += __shfl_xor(rsA, 32);
    lA += rsA;
    if (doB) { rsB += __shfl_xor(rsB, 16); rsB += __shfl_xor(rsB, 32); lB += rsB; }

    if (more) __syncthreads();                 // drains stage(t+1); buf reuse safe
    buf ^= 1;
  }

  auto epilogue = [&](const f32x4* o, float l_run, int qbase) {
    const float inv = 1.0f / l_run;
    u16* orow = op + ((size_t)bb * L_ + qbase + w * 16 + li) * D_ + hh * E_;
#pragma unroll
    for (int nc = 0; nc < 4; ++nc) {
      union { s16x4 v; unsigned u[2]; } P;
      P.u[0] = pkbf(o[nc][0] * inv, o[nc][1] * inv);
      P.u[1] = pkbf(o[nc][2] * inv, o[nc][3] * inv);
      *(s16x4*)&orow[nc * 16 + g * 4] = P.v;
    }
  };
  epilogue(oA, lA, qbaseA);
  epilogue(oB, lB, qbaseB);
}

extern "C" void kernel_launch(void* const* d_in, const int* in_sizes, int n_in,
                              void* d_out, int out_size, void* d_ws, size_t ws_size,
                              hipStream_t stream) {
  const float* queries = (const float*)d_in[0];
  const float* keys    = (const float*)d_in[1];
  const float* values  = (const float*)d_in[2];
  // d_in[3] = attn_mask: exact causal triu(k=1), applied analytically.
  const float* Wq = (const float*)d_in[4];
  const float* bq = (const float*)d_in[5];
  const float* Wk = (const float*)d_in[6];
  const float* bk = (const float*)d_in[7];
  const float* Wv = (const float*)d_in[8];
  const float* bv = (const float*)d_in[9];
  const float* Wo = (const float*)d_in[10];
  const float* bo = (const float*)d_in[11];

  const size_t MD = (size_t)8192 * 1024;   // activation elems
  const size_t WN = (size_t)1024 * 1024;   // weight elems
  u16* qbuf = (u16*)d_ws;
  u16* kbuf = qbuf + MD;
  u16* vbuf = kbuf + MD;
  u16* abuf = vbuf + MD;

  dim3 blk(256);
  dim3 ggrid(8, 64);

  const size_t need = (4 * MD + 4 * WN) * sizeof(u16);
  if (ws_size >= need) {
    u16* qcv = abuf;
    u16* kcv = qbuf;
    u16* vcv = kbuf;
    u16* wqb = abuf + MD;
    u16* wkb = wqb + WN;
    u16* wvb = wkb + WN;
    u16* wob = wvb + WN;

    cvtbf<<<dim3(4096), blk, 0, stream>>>(queries, qcv, (int)(MD / 8));
    cvtbf<<<dim3(4096), blk, 0, stream>>>(keys,    kcv, (int)(MD / 8));
    cvtbf<<<dim3(4096), blk, 0, stream>>>(values,  vcv, (int)(MD / 8));
    cvtbf<<<dim3(512),  blk, 0, stream>>>(Wq, wqb, (int)(WN / 8));
    cvtbf<<<dim3(512),  blk, 0, stream>>>(Wk, wkb, (int)(WN / 8));
    cvtbf<<<dim3(512),  blk, 0, stream>>>(Wv, wvb, (int)(WN / 8));
    cvtbf<<<dim3(512),  blk, 0, stream>>>(Wo, wob, (int)(WN / 8));

    gemm_lds<2><<<ggrid, blk, 0, stream>>>(vcv, wvb, bv, vbuf, 8192, 1024, 1024);
    gemm_lds<1><<<ggrid, blk, 0, stream>>>(kcv, wkb, bk, kbuf, 8192, 1024, 1024);
    gemm_lds<1><<<ggrid, blk, 0, stream>>>(qcv, wqb, bq, qbuf, 8192, 1024, 1024);
    attn_kernel<<<dim3(1024), blk, 0, stream>>>(qbuf, kbuf, vbuf, abuf);
    gemm_lds<0><<<ggrid, blk, 0, stream>>>(abuf, wob, bo, d_out, 8192, 1024, 1024);
  } else {
    gemm_bt<0, 1><<<ggrid, blk, 0, stream>>>(queries, Wq, bq, qbuf, 8192, 1024, 1024);
    gemm_bt<0, 1><<<ggrid, blk, 0, stream>>>(keys,    Wk, bk, kbuf, 8192, 1024, 1024);
    gemm_bt<0, 2><<<ggrid, blk, 0, stream>>>(values,  Wv, bv, vbuf, 8192, 1024, 1024);
    attn_kernel<<<dim3(1024), blk, 0, stream>>>(qbuf, kbuf, vbuf, abuf);
    gemm_bt<1, 0><<<ggrid, blk, 0, stream>>>(abuf, Wo, bo, d_out, 8192, 1024, 1024);
  }
}